// Round 5
// baseline (291.400 us; speedup 1.0000x reference)
//
#include <hip/hip_runtime.h>

#define N_NODES 50000
#define N_EDGES 600000
#define HDIM 128
#define EPS 1e-5f

typedef __attribute__((ext_vector_type(8))) short bf16x8;
typedef __attribute__((ext_vector_type(4))) float f32x4;

// ---------------- edge_index dtype detection (int32 vs int64) ----------------
__global__ void detect_kernel(const int* __restrict__ ei, int* __restrict__ flag) {
    __shared__ int nonzero;
    if (threadIdx.x == 0) nonzero = 0;
    __syncthreads();
    int acc = 0;
    for (int i = threadIdx.x; i < 1024; i += blockDim.x)
        acc |= ei[2 * i + 1];
    if (acc) atomicOr(&nonzero, 1);
    __syncthreads();
    if (threadIdx.x == 0) *flag = (nonzero == 0) ? 1 : 0;
}

__device__ __forceinline__ int load_idx(const int* __restrict__ ei, int pos, int f) {
    return f ? ei[2 * pos] : ei[pos];
}

// ---------------- degree / CSR build ----------------
__global__ void deg_kernel(const int* __restrict__ ei, const int* __restrict__ flag,
                           int* __restrict__ deg) {
    int e = blockIdx.x * blockDim.x + threadIdx.x;
    if (e >= N_EDGES) return;
    int f = *flag;
    int d = load_idx(ei, N_EDGES + e, f);
    atomicAdd(&deg[d], 1);
}

// block_sum + dinv fused (dinv needs only deg[i])
__global__ void block_sum(const int* __restrict__ deg, int* __restrict__ bsum,
                          float* __restrict__ dinv) {
    __shared__ int sm[256];
    int i = blockIdx.x * 256 + threadIdx.x;
    int d = (i < N_NODES) ? deg[i] : 0;
    if (i < N_NODES) dinv[i] = rsqrtf((float)d + 1.0f); // +1 self-loop
    sm[threadIdx.x] = d;
    __syncthreads();
    for (int s = 128; s > 0; s >>= 1) {
        if (threadIdx.x < s) sm[threadIdx.x] += sm[threadIdx.x + s];
        __syncthreads();
    }
    if (threadIdx.x == 0) bsum[blockIdx.x] = sm[0];
}

__global__ void scan_bsums(const int* __restrict__ bsum, int* __restrict__ boff, int nb) {
    __shared__ int sm[256];
    int t = threadIdx.x;
    int v = (t < nb) ? bsum[t] : 0;
    sm[t] = v;
    __syncthreads();
    for (int s = 1; s < 256; s <<= 1) {
        int add = (t >= s) ? sm[t - s] : 0;
        __syncthreads();
        sm[t] += add;
        __syncthreads();
    }
    if (t < nb) boff[t] = sm[t] - v; // exclusive
}

__global__ void scan_block(const int* __restrict__ deg, const int* __restrict__ boff,
                           int* __restrict__ rowst) {
    __shared__ int sm[256];
    int t = threadIdx.x;
    int i = blockIdx.x * 256 + t;
    int v = (i < N_NODES) ? deg[i] : 0;
    sm[t] = v;
    __syncthreads();
    for (int s = 1; s < 256; s <<= 1) {
        int add = (t >= s) ? sm[t - s] : 0;
        __syncthreads();
        sm[t] += add;
        __syncthreads();
    }
    int excl = boff[blockIdx.x] + sm[t] - v;
    if (i < N_NODES) rowst[i] = excl;
    if (i == N_NODES - 1) rowst[N_NODES] = excl + v;
}

// scatter: single packed 8B store per edge {src, bits(dinv[src])}; pad tail 16
__global__ void scatter_kernel(const int* __restrict__ ei, const int* __restrict__ flag,
                               const int* __restrict__ rowst, const float* __restrict__ dinv,
                               int* __restrict__ fill, int2* __restrict__ ecsr) {
    int e = blockIdx.x * blockDim.x + threadIdx.x;
    if (e >= N_EDGES) return;
    if (e < 16) ecsr[N_EDGES + e] = make_int2(0, 0);
    int f = *flag;
    int s = load_idx(ei, e, f);
    int d = load_idx(ei, N_EDGES + e, f);
    int pos = rowst[d] + atomicAdd(&fill[d], 1);
    ecsr[pos] = make_int2(s, __float_as_int(dinv[s]));
}

// ---------------- aggregation: 2 nodes/wave, 8-deep gather pipeline ----------------
__global__ __launch_bounds__(256, 8) void agg_kernel(const float* __restrict__ h,
                                                     const float* __restrict__ dinv,
                                                     const int* __restrict__ rowst,
                                                     const int2* __restrict__ ecsr,
                                                     float* __restrict__ out) {
    int node = blockIdx.x * 8 + (threadIdx.x >> 5);
    int sub = threadIdx.x & 31;
    if (node >= N_NODES) return;
    const float4* h4 = (const float4*)h;
    float dd = dinv[node];
    float4 v = h4[(size_t)node * 32 + sub];
    float ax = dd * v.x, ay = dd * v.y, az = dd * v.z, aw = dd * v.w; // self (×dd below)
    int e1 = rowst[node + 1];
    for (int e = rowst[node]; e < e1; e += 8) {
        int si[8];
        float wi[8];
#pragma unroll
        for (int i = 0; i < 8; ++i) {
            int2 p = ecsr[e + i];               // padded: always readable
            bool ok = (e + i < e1);
            si[i] = ok ? p.x : node;            // clamp to own row (L1-hot)
            wi[i] = ok ? __int_as_float(p.y) : 0.f;
        }
        float4 u[8];
#pragma unroll
        for (int i = 0; i < 8; ++i) u[i] = h4[(size_t)si[i] * 32 + sub];
#pragma unroll
        for (int i = 0; i < 8; ++i) {
            ax += wi[i] * u[i].x; ay += wi[i] * u[i].y;
            az += wi[i] * u[i].z; aw += wi[i] * u[i].w;
        }
    }
    float4 r;
    r.x = ax * dd; r.y = ay * dd; r.z = az * dd; r.w = aw * dd;
    ((float4*)out)[(size_t)node * 32 + sub] = r;
}

// ---------------- bf16 hi/lo split ----------------
__device__ __forceinline__ void bsplit(float a, short& hi, short& lo) {
    unsigned u = __float_as_uint(a);
    unsigned r = (u + 0x7FFFu + ((u >> 16) & 1u)) & 0xFFFF0000u; // RNE
    hi = (short)(r >> 16);
    float l = a - __uint_as_float(r);
    unsigned ul = __float_as_uint(l);
    unsigned rl = ul + 0x7FFFu + ((ul >> 16) & 1u);
    lo = (short)(rl >> 16);
}

// ---------------- pack W [128][128] fp32 -> per-lane MFMA B-fragments (hi/lo bf16) ----------------
// frag index = ((ks*8 + cf)*64 + lane)*8; lane holds B[ks*32 + (lane>>4)*8 + i][cf*16 + (lane&15)]
__global__ void pack_w(const float* __restrict__ W0, const float* __restrict__ W1,
                       const float* __restrict__ W2, const float* __restrict__ W3,
                       short* __restrict__ pkh, short* __restrict__ pkl) {
    const float* W = (blockIdx.y == 0) ? W0 : (blockIdx.y == 1) ? W1
                   : (blockIdx.y == 2) ? W2 : W3;
    int idx = blockIdx.x * 256 + threadIdx.x; // 0..2047
    int lane = idx & 63;
    int cf = (idx >> 6) & 7;
    int ks = idx >> 9;
    int col = cf * 16 + (lane & 15);
    int k0 = ks * 32 + (lane >> 4) * 8;
    short h[8], l[8];
#pragma unroll
    for (int i = 0; i < 8; ++i) bsplit(W[(size_t)(k0 + i) * HDIM + col], h[i], l[i]);
    size_t base = (size_t)blockIdx.y * 16384 + (size_t)idx * 8;
#pragma unroll
    for (int i = 0; i < 8; ++i) { pkh[base + i] = h[i]; pkl[base + i] = l[i]; }
}

// ---------------- MFMA GEMM (bf16x4 split) + epilogue ----------------
// mode 0: bias + two-pass LN (*gamma+beta) + ReLU -> out[row][col]
// mode 1: bias + ReLU, dot with w2 (gamma slot) + b2 (beta slot) -> logits out[row]
__global__ __launch_bounds__(256) void gemm_mfma(const float* __restrict__ A,
                                                 const short* __restrict__ Bh,
                                                 const short* __restrict__ Bl,
                                                 const float* __restrict__ bias,
                                                 const float* __restrict__ gamma,
                                                 const float* __restrict__ beta,
                                                 float* __restrict__ out,
                                                 int mode, int nrows) {
    int t = threadIdx.x;
    int wave = t >> 6, lane = t & 63;
    int lrow = lane & 15, lk = lane >> 4;
    int rowb = blockIdx.x * 64 + wave * 16;

    f32x4 acc[8];
#pragma unroll
    for (int cf = 0; cf < 8; ++cf) acc[cf] = (f32x4){0.f, 0.f, 0.f, 0.f};

    const float* arow = A + (size_t)(rowb + lrow) * HDIM;

#pragma unroll
    for (int ks = 0; ks < 4; ++ks) {
        const float* ap = arow + ks * 32 + lk * 8;
        float4 a0 = *(const float4*)ap;
        float4 a1 = *(const float4*)(ap + 4);
        float av[8] = {a0.x, a0.y, a0.z, a0.w, a1.x, a1.y, a1.z, a1.w};
        bf16x8 ah, al;
#pragma unroll
        for (int i = 0; i < 8; ++i) {
            short hh, ll;
            bsplit(av[i], hh, ll);
            ah[i] = hh; al[i] = ll;
        }
        const short* bhp = Bh + (size_t)(ks * 8) * 512 + (size_t)lane * 8;
        const short* blp = Bl + (size_t)(ks * 8) * 512 + (size_t)lane * 8;
#pragma unroll
        for (int cf = 0; cf < 8; ++cf) {
            bf16x8 bh = *(const bf16x8*)(bhp + (size_t)cf * 512);
            bf16x8 bl = *(const bf16x8*)(blp + (size_t)cf * 512);
            acc[cf] = __builtin_amdgcn_mfma_f32_16x16x32_bf16(ah, bh, acc[cf], 0, 0, 0);
            acc[cf] = __builtin_amdgcn_mfma_f32_16x16x32_bf16(ah, bl, acc[cf], 0, 0, 0);
            acc[cf] = __builtin_amdgcn_mfma_f32_16x16x32_bf16(al, bh, acc[cf], 0, 0, 0);
            acc[cf] = __builtin_amdgcn_mfma_f32_16x16x32_bf16(al, bl, acc[cf], 0, 0, 0);
        }
    }

    // C/D layout: col = cf*16 + lrow, local row = lk*4 + r
    float bias_v[8];
#pragma unroll
    for (int cf = 0; cf < 8; ++cf) bias_v[cf] = bias[cf * 16 + lrow];

    if (mode == 0) {
        float gam[8], bet[8];
#pragma unroll
        for (int cf = 0; cf < 8; ++cf) {
            gam[cf] = gamma[cf * 16 + lrow];
            bet[cf] = beta[cf * 16 + lrow];
        }
#pragma unroll
        for (int r = 0; r < 4; ++r) {
            float vv[8];
            float s1 = 0.f;
#pragma unroll
            for (int cf = 0; cf < 8; ++cf) {
                vv[cf] = acc[cf][r] + bias_v[cf];
                s1 += vv[cf];
            }
#pragma unroll
            for (int m = 1; m <= 8; m <<= 1) s1 += __shfl_xor(s1, m);
            float mean = s1 * (1.0f / 128.0f);
            float s2 = 0.f;
            float cc[8];
#pragma unroll
            for (int cf = 0; cf < 8; ++cf) {
                cc[cf] = vv[cf] - mean;
                s2 += cc[cf] * cc[cf];
            }
#pragma unroll
            for (int m = 1; m <= 8; m <<= 1) s2 += __shfl_xor(s2, m);
            float var = s2 * (1.0f / 128.0f);
            float rs = rsqrtf(var + EPS);
            int row = rowb + lk * 4 + r;
            if (row < nrows) {
#pragma unroll
                for (int cf = 0; cf < 8; ++cf) {
                    float y = cc[cf] * rs * gam[cf] + bet[cf];
                    out[(size_t)row * HDIM + cf * 16 + lrow] = y > 0.f ? y : 0.f;
                }
            }
        }
    } else {
        float w2v[8];
#pragma unroll
        for (int cf = 0; cf < 8; ++cf) w2v[cf] = gamma[cf * 16 + lrow];
        float b2 = beta[0];
#pragma unroll
        for (int r = 0; r < 4; ++r) {
            float part = 0.f;
#pragma unroll
            for (int cf = 0; cf < 8; ++cf) {
                float y = acc[cf][r] + bias_v[cf];
                y = y > 0.f ? y : 0.f;
                part += y * w2v[cf];
            }
#pragma unroll
            for (int m = 1; m <= 8; m <<= 1) part += __shfl_xor(part, m);
            int row = rowb + lk * 4 + r;
            if (row < nrows && lrow == 0) out[row] = part + b2;
        }
    }
}

extern "C" void kernel_launch(void* const* d_in, const int* in_sizes, int n_in,
                              void* d_out, int out_size, void* d_ws, size_t ws_size,
                              hipStream_t stream) {
    (void)in_sizes; (void)n_in; (void)out_size; (void)ws_size;
    const float* x   = (const float*)d_in[0];
    const int*   ei  = (const int*)d_in[1];
    const float* W0  = (const float*)d_in[2];
    const float* b0  = (const float*)d_in[3];
    const float* g0  = (const float*)d_in[4];
    const float* be0 = (const float*)d_in[5];
    const float* W1  = (const float*)d_in[6];
    const float* b1  = (const float*)d_in[7];
    const float* g1  = (const float*)d_in[8];
    const float* be1 = (const float*)d_in[9];
    const float* W2  = (const float*)d_in[10];
    const float* b2  = (const float*)d_in[11];
    const float* g2  = (const float*)d_in[12];
    const float* be2 = (const float*)d_in[13];
    const float* hW1 = (const float*)d_in[14];
    const float* hb1 = (const float*)d_in[15];
    const float* hW2 = (const float*)d_in[16];
    const float* hb2 = (const float*)d_in[17];
    float* out = (float*)d_out;

    char* w = (char*)d_ws;
    size_t off = 0;
    auto alloc = [&](size_t bytes) -> void* {
        void* p = w + off;
        off += (bytes + 255) & ~(size_t)255;
        return p;
    };
    float* dinv  = (float*)alloc((size_t)N_NODES * 4);
    int*   deg   = (int*)alloc((size_t)N_NODES * 4);
    int*   fill  = (int*)alloc((size_t)N_NODES * 4);
    int*   rowst = (int*)alloc((size_t)(N_NODES + 1) * 4);
    int2*  ecsr  = (int2*)alloc((size_t)(N_EDGES + 16) * 8);
    int*   bsum  = (int*)alloc(256 * 4);
    int*   boff  = (int*)alloc(256 * 4);
    int*   flag  = (int*)alloc(256);
    float* hagg  = (float*)alloc((size_t)N_NODES * HDIM * 4);
    float* hbufA = (float*)alloc((size_t)N_NODES * HDIM * 4);
    float* hbufB = (float*)alloc((size_t)N_NODES * HDIM * 4);
    short* pkh   = (short*)alloc((size_t)4 * 16384 * 2);
    short* pkl   = (short*)alloc((size_t)4 * 16384 * 2);

    hipMemsetAsync(deg, 0, (size_t)N_NODES * 4, stream);
    hipMemsetAsync(fill, 0, (size_t)N_NODES * 4, stream);

    detect_kernel<<<1, 256, 0, stream>>>(ei, flag);
    deg_kernel<<<(N_EDGES + 255) / 256, 256, 0, stream>>>(ei, flag, deg);
    int nb = (N_NODES + 255) / 256; // 196
    block_sum<<<nb, 256, 0, stream>>>(deg, bsum, dinv);
    scan_bsums<<<1, 256, 0, stream>>>(bsum, boff, nb);
    scan_block<<<nb, 256, 0, stream>>>(deg, boff, rowst);
    scatter_kernel<<<(N_EDGES + 255) / 256, 256, 0, stream>>>(ei, flag, rowst, dinv, fill, ecsr);

    dim3 pg(8, 4);
    pack_w<<<pg, 256, 0, stream>>>(W0, W1, W2, hW1, pkh, pkl);

    int nab = (N_NODES + 7) / 8;   // 6250
    int ngb = (N_NODES + 63) / 64; // 782
    const float* bs[3]  = {b0, b1, b2};
    const float* gs[3]  = {g0, g1, g2};
    const float* bes[3] = {be0, be2, be2}; // placeholder, fixed below
    bes[1] = be1;
    const float* hin = x;
    float* houts[3] = {hbufA, hbufB, hbufA};
    for (int l = 0; l < 3; ++l) {
        agg_kernel<<<nab, 256, 0, stream>>>(hin, dinv, rowst, ecsr, hagg);
        gemm_mfma<<<ngb, 256, 0, stream>>>(hagg, pkh + (size_t)l * 16384, pkl + (size_t)l * 16384,
                                           bs[l], gs[l], bes[l], houts[l], 0, N_NODES);
        hin = houts[l];
    }
    // fused head: ReLU(h @ hW1 + hb1) @ hW2 + hb2 -> logits
    gemm_mfma<<<ngb, 256, 0, stream>>>(hbufA, pkh + (size_t)3 * 16384, pkl + (size_t)3 * 16384,
                                       hb1, hW2, hb2, out, 1, N_NODES);
}

// Round 6
// 212.711 us; speedup vs baseline: 1.3699x; 1.3699x over previous
//
#include <hip/hip_runtime.h>
#include <hip/hip_fp16.h>

#define N_NODES 50000
#define N_EDGES 600000
#define HDIM 128
#define EPS 1e-5f

typedef __attribute__((ext_vector_type(8))) short bf16x8;
typedef __attribute__((ext_vector_type(4))) float f32x4;
typedef __attribute__((ext_vector_type(4))) _Float16 h16x4;
typedef __attribute__((ext_vector_type(8))) _Float16 h16x8;

// ---------------- edge_index dtype detection (int32 vs int64) ----------------
__global__ void detect_kernel(const int* __restrict__ ei, int* __restrict__ flag) {
    __shared__ int nonzero;
    if (threadIdx.x == 0) nonzero = 0;
    __syncthreads();
    int acc = 0;
    for (int i = threadIdx.x; i < 1024; i += blockDim.x)
        acc |= ei[2 * i + 1];
    if (acc) atomicOr(&nonzero, 1);
    __syncthreads();
    if (threadIdx.x == 0) *flag = (nonzero == 0) ? 1 : 0;
}

__device__ __forceinline__ int load_idx(const int* __restrict__ ei, int pos, int f) {
    return f ? ei[2 * pos] : ei[pos];
}

// ---------------- x fp32 -> fp16 ----------------
__global__ void cvt_x(const float* __restrict__ x, _Float16* __restrict__ xh) {
    int idx = blockIdx.x * 256 + threadIdx.x; // one float4 per thread
    if (idx >= N_NODES * 32) return;
    float4 v = ((const float4*)x)[idx];
    h16x4 o;
    o[0] = (_Float16)v.x; o[1] = (_Float16)v.y; o[2] = (_Float16)v.z; o[3] = (_Float16)v.w;
    ((h16x4*)xh)[idx] = o;
}

// ---------------- degree pass: also assign within-row slot (kills scatter atomic) ----------------
__global__ void deg_kernel(const int* __restrict__ ei, const int* __restrict__ flag,
                           int* __restrict__ deg, int* __restrict__ slot) {
    int e = blockIdx.x * blockDim.x + threadIdx.x;
    if (e >= N_EDGES) return;
    int f = *flag;
    int d = load_idx(ei, N_EDGES + e, f);
    slot[e] = atomicAdd(&deg[d], 1);
}

// block_sum + dinv fused
__global__ void block_sum(const int* __restrict__ deg, int* __restrict__ bsum,
                          float* __restrict__ dinv) {
    __shared__ int sm[256];
    int i = blockIdx.x * 256 + threadIdx.x;
    int d = (i < N_NODES) ? deg[i] : 0;
    if (i < N_NODES) dinv[i] = rsqrtf((float)d + 1.0f); // +1 self-loop
    sm[threadIdx.x] = d;
    __syncthreads();
    for (int s = 128; s > 0; s >>= 1) {
        if (threadIdx.x < s) sm[threadIdx.x] += sm[threadIdx.x + s];
        __syncthreads();
    }
    if (threadIdx.x == 0) bsum[blockIdx.x] = sm[0];
}

__global__ void scan_bsums(const int* __restrict__ bsum, int* __restrict__ boff, int nb) {
    __shared__ int sm[256];
    int t = threadIdx.x;
    int v = (t < nb) ? bsum[t] : 0;
    sm[t] = v;
    __syncthreads();
    for (int s = 1; s < 256; s <<= 1) {
        int add = (t >= s) ? sm[t - s] : 0;
        __syncthreads();
        sm[t] += add;
        __syncthreads();
    }
    if (t < nb) boff[t] = sm[t] - v; // exclusive
}

__global__ void scan_block(const int* __restrict__ deg, const int* __restrict__ boff,
                           int* __restrict__ rowst) {
    __shared__ int sm[256];
    int t = threadIdx.x;
    int i = blockIdx.x * 256 + t;
    int v = (i < N_NODES) ? deg[i] : 0;
    sm[t] = v;
    __syncthreads();
    for (int s = 1; s < 256; s <<= 1) {
        int add = (t >= s) ? sm[t - s] : 0;
        __syncthreads();
        sm[t] += add;
        __syncthreads();
    }
    int excl = boff[blockIdx.x] + sm[t] - v;
    if (i < N_NODES) rowst[i] = excl;
    if (i == N_NODES - 1) rowst[N_NODES] = excl + v;
}

// scatter: no atomic (slot precomputed); single packed 8B store per edge
__global__ void scatter_kernel(const int* __restrict__ ei, const int* __restrict__ flag,
                               const int* __restrict__ rowst, const float* __restrict__ dinv,
                               const int* __restrict__ slot, int2* __restrict__ ecsr) {
    int e = blockIdx.x * blockDim.x + threadIdx.x;
    if (e >= N_EDGES) return;
    if (e < 16) ecsr[N_EDGES + e] = make_int2(0, 0);
    int f = *flag;
    int s = load_idx(ei, e, f);
    int d = load_idx(ei, N_EDGES + e, f);
    int pos = rowst[d] + slot[e];
    ecsr[pos] = make_int2(s, __float_as_int(dinv[s]));
}

// ---------------- aggregation over fp16 h: 2 nodes/wave, 4-deep predicated ----------------
__global__ __launch_bounds__(256) void agg_kernel(const _Float16* __restrict__ h,
                                                  const float* __restrict__ dinv,
                                                  const int* __restrict__ rowst,
                                                  const int2* __restrict__ ecsr,
                                                  float* __restrict__ out) {
    int node = blockIdx.x * 8 + (threadIdx.x >> 5);
    int sub = threadIdx.x & 31;
    if (node >= N_NODES) return;
    const h16x4* h4 = (const h16x4*)h;
    float dd = dinv[node];
    h16x4 v = h4[(size_t)node * 32 + sub];
    float ax = dd * (float)v[0], ay = dd * (float)v[1];
    float az = dd * (float)v[2], aw = dd * (float)v[3]; // self (×dd below)
    int e1 = rowst[node + 1];
    for (int e = rowst[node]; e < e1; e += 4) {
        int2 p0 = ecsr[e];
        int2 p1 = ecsr[e + 1];
        int2 p2 = ecsr[e + 2];
        int2 p3 = ecsr[e + 3];
        int s0 = p0.x;
        float w0 = __int_as_float(p0.y);
        int s1 = (e + 1 < e1) ? p1.x : s0;
        float w1 = (e + 1 < e1) ? __int_as_float(p1.y) : 0.f;
        int s2 = (e + 2 < e1) ? p2.x : s0;
        float w2 = (e + 2 < e1) ? __int_as_float(p2.y) : 0.f;
        int s3 = (e + 3 < e1) ? p3.x : s0;
        float w3 = (e + 3 < e1) ? __int_as_float(p3.y) : 0.f;
        h16x4 u0 = h4[(size_t)s0 * 32 + sub];
        h16x4 u1 = h4[(size_t)s1 * 32 + sub];
        h16x4 u2 = h4[(size_t)s2 * 32 + sub];
        h16x4 u3 = h4[(size_t)s3 * 32 + sub];
        ax += w0 * (float)u0[0]; ay += w0 * (float)u0[1]; az += w0 * (float)u0[2]; aw += w0 * (float)u0[3];
        ax += w1 * (float)u1[0]; ay += w1 * (float)u1[1]; az += w1 * (float)u1[2]; aw += w1 * (float)u1[3];
        ax += w2 * (float)u2[0]; ay += w2 * (float)u2[1]; az += w2 * (float)u2[2]; aw += w2 * (float)u2[3];
        ax += w3 * (float)u3[0]; ay += w3 * (float)u3[1]; az += w3 * (float)u3[2]; aw += w3 * (float)u3[3];
    }
    float4 r;
    r.x = ax * dd; r.y = ay * dd; r.z = az * dd; r.w = aw * dd;
    ((float4*)out)[(size_t)node * 32 + sub] = r;
}

// ---------------- bf16 hi/lo split ----------------
__device__ __forceinline__ void bsplit(float a, short& hi, short& lo) {
    unsigned u = __float_as_uint(a);
    unsigned r = (u + 0x7FFFu + ((u >> 16) & 1u)) & 0xFFFF0000u; // RNE
    hi = (short)(r >> 16);
    float l = a - __uint_as_float(r);
    unsigned ul = __float_as_uint(l);
    unsigned rl = ul + 0x7FFFu + ((ul >> 16) & 1u);
    lo = (short)(rl >> 16);
}

// ---------------- pack W [128][128] fp32 -> per-lane MFMA B-fragments (hi/lo bf16) ----------------
__global__ void pack_w(const float* __restrict__ W0, const float* __restrict__ W1,
                       const float* __restrict__ W2, const float* __restrict__ W3,
                       short* __restrict__ pkh, short* __restrict__ pkl) {
    const float* W = (blockIdx.y == 0) ? W0 : (blockIdx.y == 1) ? W1
                   : (blockIdx.y == 2) ? W2 : W3;
    int idx = blockIdx.x * 256 + threadIdx.x; // 0..2047
    int lane = idx & 63;
    int cf = (idx >> 6) & 7;
    int ks = idx >> 9;
    int col = cf * 16 + (lane & 15);
    int k0 = ks * 32 + (lane >> 4) * 8;
    short h[8], l[8];
#pragma unroll
    for (int i = 0; i < 8; ++i) bsplit(W[(size_t)(k0 + i) * HDIM + col], h[i], l[i]);
    size_t base = (size_t)blockIdx.y * 16384 + (size_t)idx * 8;
#pragma unroll
    for (int i = 0; i < 8; ++i) { pkh[base + i] = h[i]; pkl[base + i] = l[i]; }
}

// ---------------- MFMA GEMM (bf16x4 split) + epilogue ----------------
// AHALF: A rows are fp16 (else fp32)
// mode 0: bias + two-pass LN (*gamma+beta) + ReLU -> fp16 out[row][col]
// mode 1: bias + ReLU, dot w2 + b2 -> fp32 logits out[row]
template <bool AHALF>
__global__ __launch_bounds__(256) void gemm_mfma(const void* __restrict__ Araw,
                                                 const short* __restrict__ Bh,
                                                 const short* __restrict__ Bl,
                                                 const float* __restrict__ bias,
                                                 const float* __restrict__ gamma,
                                                 const float* __restrict__ beta,
                                                 void* __restrict__ outraw,
                                                 int mode, int nrows) {
    int t = threadIdx.x;
    int wave = t >> 6, lane = t & 63;
    int lrow = lane & 15, lk = lane >> 4;
    int rowb = blockIdx.x * 64 + wave * 16;

    f32x4 acc[8];
#pragma unroll
    for (int cf = 0; cf < 8; ++cf) acc[cf] = (f32x4){0.f, 0.f, 0.f, 0.f};

#pragma unroll
    for (int ks = 0; ks < 4; ++ks) {
        float av[8];
        if (AHALF) {
            const _Float16* arow = (const _Float16*)Araw + (size_t)(rowb + lrow) * HDIM;
            h16x8 a = *(const h16x8*)(arow + ks * 32 + lk * 8);
#pragma unroll
            for (int i = 0; i < 8; ++i) av[i] = (float)a[i];
        } else {
            const float* arow = (const float*)Araw + (size_t)(rowb + lrow) * HDIM;
            float4 a0 = *(const float4*)(arow + ks * 32 + lk * 8);
            float4 a1 = *(const float4*)(arow + ks * 32 + lk * 8 + 4);
            av[0] = a0.x; av[1] = a0.y; av[2] = a0.z; av[3] = a0.w;
            av[4] = a1.x; av[5] = a1.y; av[6] = a1.z; av[7] = a1.w;
        }
        bf16x8 ah, al;
#pragma unroll
        for (int i = 0; i < 8; ++i) {
            short hh, ll;
            bsplit(av[i], hh, ll);
            ah[i] = hh; al[i] = ll;
        }
        const short* bhp = Bh + (size_t)(ks * 8) * 512 + (size_t)lane * 8;
        const short* blp = Bl + (size_t)(ks * 8) * 512 + (size_t)lane * 8;
#pragma unroll
        for (int cf = 0; cf < 8; ++cf) {
            bf16x8 bh = *(const bf16x8*)(bhp + (size_t)cf * 512);
            bf16x8 bl = *(const bf16x8*)(blp + (size_t)cf * 512);
            acc[cf] = __builtin_amdgcn_mfma_f32_16x16x32_bf16(ah, bh, acc[cf], 0, 0, 0);
            acc[cf] = __builtin_amdgcn_mfma_f32_16x16x32_bf16(ah, bl, acc[cf], 0, 0, 0);
            acc[cf] = __builtin_amdgcn_mfma_f32_16x16x32_bf16(al, bh, acc[cf], 0, 0, 0);
            acc[cf] = __builtin_amdgcn_mfma_f32_16x16x32_bf16(al, bl, acc[cf], 0, 0, 0);
        }
    }

    // C/D layout: col = cf*16 + lrow, local row = lk*4 + r
    float bias_v[8];
#pragma unroll
    for (int cf = 0; cf < 8; ++cf) bias_v[cf] = bias[cf * 16 + lrow];

    if (mode == 0) {
        _Float16* out = (_Float16*)outraw;
        float gam[8], bet[8];
#pragma unroll
        for (int cf = 0; cf < 8; ++cf) {
            gam[cf] = gamma[cf * 16 + lrow];
            bet[cf] = beta[cf * 16 + lrow];
        }
#pragma unroll
        for (int r = 0; r < 4; ++r) {
            float vv[8];
            float s1 = 0.f;
#pragma unroll
            for (int cf = 0; cf < 8; ++cf) {
                vv[cf] = acc[cf][r] + bias_v[cf];
                s1 += vv[cf];
            }
#pragma unroll
            for (int m = 1; m <= 8; m <<= 1) s1 += __shfl_xor(s1, m);
            float mean = s1 * (1.0f / 128.0f);
            float s2 = 0.f;
            float cc[8];
#pragma unroll
            for (int cf = 0; cf < 8; ++cf) {
                cc[cf] = vv[cf] - mean;
                s2 += cc[cf] * cc[cf];
            }
#pragma unroll
            for (int m = 1; m <= 8; m <<= 1) s2 += __shfl_xor(s2, m);
            float var = s2 * (1.0f / 128.0f);
            float rs = rsqrtf(var + EPS);
            int row = rowb + lk * 4 + r;
            if (row < nrows) {
#pragma unroll
                for (int cf = 0; cf < 8; ++cf) {
                    float y = cc[cf] * rs * gam[cf] + bet[cf];
                    out[(size_t)row * HDIM + cf * 16 + lrow] = (_Float16)(y > 0.f ? y : 0.f);
                }
            }
        }
    } else {
        float* out = (float*)outraw;
        float w2v[8];
#pragma unroll
        for (int cf = 0; cf < 8; ++cf) w2v[cf] = gamma[cf * 16 + lrow];
        float b2 = beta[0];
#pragma unroll
        for (int r = 0; r < 4; ++r) {
            float part = 0.f;
#pragma unroll
            for (int cf = 0; cf < 8; ++cf) {
                float y = acc[cf][r] + bias_v[cf];
                y = y > 0.f ? y : 0.f;
                part += y * w2v[cf];
            }
#pragma unroll
            for (int m = 1; m <= 8; m <<= 1) part += __shfl_xor(part, m);
            int row = rowb + lk * 4 + r;
            if (row < nrows && lrow == 0) out[row] = part + b2;
        }
    }
}

extern "C" void kernel_launch(void* const* d_in, const int* in_sizes, int n_in,
                              void* d_out, int out_size, void* d_ws, size_t ws_size,
                              hipStream_t stream) {
    (void)in_sizes; (void)n_in; (void)out_size; (void)ws_size;
    const float* x   = (const float*)d_in[0];
    const int*   ei  = (const int*)d_in[1];
    const float* W0  = (const float*)d_in[2];
    const float* b0  = (const float*)d_in[3];
    const float* g0  = (const float*)d_in[4];
    const float* be0 = (const float*)d_in[5];
    const float* W1  = (const float*)d_in[6];
    const float* b1  = (const float*)d_in[7];
    const float* g1  = (const float*)d_in[8];
    const float* be1 = (const float*)d_in[9];
    const float* W2  = (const float*)d_in[10];
    const float* b2  = (const float*)d_in[11];
    const float* g2  = (const float*)d_in[12];
    const float* be2 = (const float*)d_in[13];
    const float* hW1 = (const float*)d_in[14];
    const float* hb1 = (const float*)d_in[15];
    const float* hW2 = (const float*)d_in[16];
    const float* hb2 = (const float*)d_in[17];
    float* out = (float*)d_out;

    char* w = (char*)d_ws;
    size_t off = 0;
    auto alloc = [&](size_t bytes) -> void* {
        void* p = w + off;
        off += (bytes + 255) & ~(size_t)255;
        return p;
    };
    float*     dinv  = (float*)alloc((size_t)N_NODES * 4);
    int*       deg   = (int*)alloc((size_t)N_NODES * 4);
    int*       rowst = (int*)alloc((size_t)(N_NODES + 1) * 4);
    int*       slot  = (int*)alloc((size_t)N_EDGES * 4);
    int2*      ecsr  = (int2*)alloc((size_t)(N_EDGES + 16) * 8);
    int*       bsum  = (int*)alloc(256 * 4);
    int*       boff  = (int*)alloc(256 * 4);
    int*       flag  = (int*)alloc(256);
    float*     hagg  = (float*)alloc((size_t)N_NODES * HDIM * 4);
    _Float16*  xh    = (_Float16*)alloc((size_t)N_NODES * HDIM * 2);
    _Float16*  hA    = (_Float16*)alloc((size_t)N_NODES * HDIM * 2);
    _Float16*  hB    = (_Float16*)alloc((size_t)N_NODES * HDIM * 2);
    short*     pkh   = (short*)alloc((size_t)4 * 16384 * 2);
    short*     pkl   = (short*)alloc((size_t)4 * 16384 * 2);

    hipMemsetAsync(deg, 0, (size_t)N_NODES * 4, stream);

    detect_kernel<<<1, 256, 0, stream>>>(ei, flag);
    cvt_x<<<(N_NODES * 32 + 255) / 256, 256, 0, stream>>>(x, xh);
    deg_kernel<<<(N_EDGES + 255) / 256, 256, 0, stream>>>(ei, flag, deg, slot);
    int nb = (N_NODES + 255) / 256; // 196
    block_sum<<<nb, 256, 0, stream>>>(deg, bsum, dinv);
    scan_bsums<<<1, 256, 0, stream>>>(bsum, boff, nb);
    scan_block<<<nb, 256, 0, stream>>>(deg, boff, rowst);
    scatter_kernel<<<(N_EDGES + 255) / 256, 256, 0, stream>>>(ei, flag, rowst, dinv, slot, ecsr);

    dim3 pg(8, 4);
    pack_w<<<pg, 256, 0, stream>>>(W0, W1, W2, hW1, pkh, pkl);

    int nab = (N_NODES + 7) / 8;   // 6250
    int ngb = (N_NODES + 63) / 64; // 782
    // layer 0: xh -> hagg -> hA
    agg_kernel<<<nab, 256, 0, stream>>>(xh, dinv, rowst, ecsr, hagg);
    gemm_mfma<false><<<ngb, 256, 0, stream>>>(hagg, pkh, pkl, b0, g0, be0, hA, 0, N_NODES);
    // layer 1: hA -> hagg -> hB
    agg_kernel<<<nab, 256, 0, stream>>>(hA, dinv, rowst, ecsr, hagg);
    gemm_mfma<false><<<ngb, 256, 0, stream>>>(hagg, pkh + (size_t)16384, pkl + (size_t)16384,
                                              b1, g1, be1, hB, 0, N_NODES);
    // layer 2: hB -> hagg -> hA
    agg_kernel<<<nab, 256, 0, stream>>>(hB, dinv, rowst, ecsr, hagg);
    gemm_mfma<false><<<ngb, 256, 0, stream>>>(hagg, pkh + (size_t)2 * 16384, pkl + (size_t)2 * 16384,
                                              b2, g2, be2, hA, 0, N_NODES);
    // fused head: ReLU(hA @ hW1 + hb1) @ hW2 + hb2 -> logits
    gemm_mfma<true><<<ngb, 256, 0, stream>>>(hA, pkh + (size_t)3 * 16384, pkl + (size_t)3 * 16384,
                                             hb1, hW2, hb2, out, 1, N_NODES);
}

// Round 7
// 204.608 us; speedup vs baseline: 1.4242x; 1.0396x over previous
//
#include <hip/hip_runtime.h>
#include <hip/hip_fp16.h>

#define N_NODES 50000
#define N_EDGES 600000
#define HDIM 128
#define EPS 1e-5f

typedef __attribute__((ext_vector_type(8))) short bf16x8;
typedef __attribute__((ext_vector_type(4))) float f32x4;
typedef __attribute__((ext_vector_type(4))) _Float16 h16x4;
typedef __attribute__((ext_vector_type(8))) _Float16 h16x8;

// ---------------- edge_index dtype detection (int32 vs int64) ----------------
__global__ void detect_kernel(const int* __restrict__ ei, int* __restrict__ flag) {
    __shared__ int nonzero;
    if (threadIdx.x == 0) nonzero = 0;
    __syncthreads();
    int acc = 0;
    for (int i = threadIdx.x; i < 1024; i += blockDim.x)
        acc |= ei[2 * i + 1];
    if (acc) atomicOr(&nonzero, 1);
    __syncthreads();
    if (threadIdx.x == 0) *flag = (nonzero == 0) ? 1 : 0;
}

__device__ __forceinline__ int load_idx(const int* __restrict__ ei, int pos, int f) {
    return f ? ei[2 * pos] : ei[pos];
}

// ---------------- x fp32 -> fp16 ----------------
__global__ void cvt_x(const float* __restrict__ x, _Float16* __restrict__ xh) {
    int idx = blockIdx.x * 256 + threadIdx.x; // one float4 per thread
    if (idx >= N_NODES * 32) return;
    float4 v = ((const float4*)x)[idx];
    h16x4 o;
    o[0] = (_Float16)v.x; o[1] = (_Float16)v.y; o[2] = (_Float16)v.z; o[3] = (_Float16)v.w;
    ((h16x4*)xh)[idx] = o;
}

// ---------------- degree pass: also assign within-row slot ----------------
__global__ void deg_kernel(const int* __restrict__ ei, const int* __restrict__ flag,
                           int* __restrict__ deg, int* __restrict__ slot) {
    int e = blockIdx.x * blockDim.x + threadIdx.x;
    if (e >= N_EDGES) return;
    int f = *flag;
    int d = load_idx(ei, N_EDGES + e, f);
    slot[e] = atomicAdd(&deg[d], 1);
}

// block_sum + dinv fused
__global__ void block_sum(const int* __restrict__ deg, int* __restrict__ bsum,
                          float* __restrict__ dinv) {
    __shared__ int sm[256];
    int i = blockIdx.x * 256 + threadIdx.x;
    int d = (i < N_NODES) ? deg[i] : 0;
    if (i < N_NODES) dinv[i] = rsqrtf((float)d + 1.0f); // +1 self-loop
    sm[threadIdx.x] = d;
    __syncthreads();
    for (int s = 128; s > 0; s >>= 1) {
        if (threadIdx.x < s) sm[threadIdx.x] += sm[threadIdx.x + s];
        __syncthreads();
    }
    if (threadIdx.x == 0) bsum[blockIdx.x] = sm[0];
}

__global__ void scan_bsums(const int* __restrict__ bsum, int* __restrict__ boff, int nb) {
    __shared__ int sm[256];
    int t = threadIdx.x;
    int v = (t < nb) ? bsum[t] : 0;
    sm[t] = v;
    __syncthreads();
    for (int s = 1; s < 256; s <<= 1) {
        int add = (t >= s) ? sm[t - s] : 0;
        __syncthreads();
        sm[t] += add;
        __syncthreads();
    }
    if (t < nb) boff[t] = sm[t] - v; // exclusive
}

__global__ void scan_block(const int* __restrict__ deg, const int* __restrict__ boff,
                           int* __restrict__ rowst) {
    __shared__ int sm[256];
    int t = threadIdx.x;
    int i = blockIdx.x * 256 + t;
    int v = (i < N_NODES) ? deg[i] : 0;
    sm[t] = v;
    __syncthreads();
    for (int s = 1; s < 256; s <<= 1) {
        int add = (t >= s) ? sm[t - s] : 0;
        __syncthreads();
        sm[t] += add;
        __syncthreads();
    }
    int excl = boff[blockIdx.x] + sm[t] - v;
    if (i < N_NODES) rowst[i] = excl;
    if (i == N_NODES - 1) rowst[N_NODES] = excl + v;
}

// scatter: 4B packed store per edge {fp16(dinv[src]) << 16 | src}
__global__ void scatter_kernel(const int* __restrict__ ei, const int* __restrict__ flag,
                               const int* __restrict__ rowst, const float* __restrict__ dinv,
                               const int* __restrict__ slot, unsigned* __restrict__ ecsr) {
    int e = blockIdx.x * blockDim.x + threadIdx.x;
    if (e >= N_EDGES) return;
    if (e < 16) ecsr[N_EDGES + e] = 0u;
    int f = *flag;
    int s = load_idx(ei, e, f);
    int d = load_idx(ei, N_EDGES + e, f);
    int pos = rowst[d] + slot[e];
    _Float16 wv = (_Float16)dinv[s];
    unsigned wb = (unsigned)__builtin_bit_cast(unsigned short, wv);
    ecsr[pos] = (wb << 16) | (unsigned)s;
}

__device__ __forceinline__ float unpack_w(unsigned p) {
    unsigned short b = (unsigned short)(p >> 16);
    return (float)__builtin_bit_cast(_Float16, b);
}

// ---------------- aggregation over fp16 h: 2 nodes/wave, 4-deep predicated ----------------
__global__ __launch_bounds__(256) void agg_kernel(const _Float16* __restrict__ h,
                                                  const float* __restrict__ dinv,
                                                  const int* __restrict__ rowst,
                                                  const unsigned* __restrict__ ecsr,
                                                  _Float16* __restrict__ out) {
    int node = blockIdx.x * 8 + (threadIdx.x >> 5);
    int sub = threadIdx.x & 31;
    if (node >= N_NODES) return;
    const h16x4* h4 = (const h16x4*)h;
    float dd = dinv[node];
    h16x4 v = h4[(size_t)node * 32 + sub];
    float ax = dd * (float)v[0], ay = dd * (float)v[1];
    float az = dd * (float)v[2], aw = dd * (float)v[3]; // self (×dd below)
    int e1 = rowst[node + 1];
    for (int e = rowst[node]; e < e1; e += 4) {
        unsigned p0 = ecsr[e];
        unsigned p1 = ecsr[e + 1];
        unsigned p2 = ecsr[e + 2];
        unsigned p3 = ecsr[e + 3];
        int s0 = p0 & 0xFFFFu;
        float w0 = unpack_w(p0);
        int s1 = (e + 1 < e1) ? (int)(p1 & 0xFFFFu) : s0;
        float w1 = (e + 1 < e1) ? unpack_w(p1) : 0.f;
        int s2 = (e + 2 < e1) ? (int)(p2 & 0xFFFFu) : s0;
        float w2 = (e + 2 < e1) ? unpack_w(p2) : 0.f;
        int s3 = (e + 3 < e1) ? (int)(p3 & 0xFFFFu) : s0;
        float w3 = (e + 3 < e1) ? unpack_w(p3) : 0.f;
        h16x4 u0 = h4[(size_t)s0 * 32 + sub];
        h16x4 u1 = h4[(size_t)s1 * 32 + sub];
        h16x4 u2 = h4[(size_t)s2 * 32 + sub];
        h16x4 u3 = h4[(size_t)s3 * 32 + sub];
        ax += w0 * (float)u0[0]; ay += w0 * (float)u0[1]; az += w0 * (float)u0[2]; aw += w0 * (float)u0[3];
        ax += w1 * (float)u1[0]; ay += w1 * (float)u1[1]; az += w1 * (float)u1[2]; aw += w1 * (float)u1[3];
        ax += w2 * (float)u2[0]; ay += w2 * (float)u2[1]; az += w2 * (float)u2[2]; aw += w2 * (float)u2[3];
        ax += w3 * (float)u3[0]; ay += w3 * (float)u3[1]; az += w3 * (float)u3[2]; aw += w3 * (float)u3[3];
    }
    h16x4 r;
    r[0] = (_Float16)(ax * dd); r[1] = (_Float16)(ay * dd);
    r[2] = (_Float16)(az * dd); r[3] = (_Float16)(aw * dd);
    ((h16x4*)out)[(size_t)node * 32 + sub] = r;
}

// ---------------- bf16 hi/lo split ----------------
__device__ __forceinline__ void bsplit(float a, short& hi, short& lo) {
    unsigned u = __float_as_uint(a);
    unsigned r = (u + 0x7FFFu + ((u >> 16) & 1u)) & 0xFFFF0000u; // RNE
    hi = (short)(r >> 16);
    float l = a - __uint_as_float(r);
    unsigned ul = __float_as_uint(l);
    unsigned rl = ul + 0x7FFFu + ((ul >> 16) & 1u);
    lo = (short)(rl >> 16);
}

// ---------------- pack W [128][128] fp32 -> per-lane MFMA B-fragments (hi/lo bf16) ----------------
__global__ void pack_w(const float* __restrict__ W0, const float* __restrict__ W1,
                       const float* __restrict__ W2, const float* __restrict__ W3,
                       short* __restrict__ pkh, short* __restrict__ pkl) {
    const float* W = (blockIdx.y == 0) ? W0 : (blockIdx.y == 1) ? W1
                   : (blockIdx.y == 2) ? W2 : W3;
    int idx = blockIdx.x * 256 + threadIdx.x; // 0..2047
    int lane = idx & 63;
    int cf = (idx >> 6) & 7;
    int ks = idx >> 9;
    int col = cf * 16 + (lane & 15);
    int k0 = ks * 32 + (lane >> 4) * 8;
    short h[8], l[8];
#pragma unroll
    for (int i = 0; i < 8; ++i) bsplit(W[(size_t)(k0 + i) * HDIM + col], h[i], l[i]);
    size_t base = (size_t)blockIdx.y * 16384 + (size_t)idx * 8;
#pragma unroll
    for (int i = 0; i < 8; ++i) { pkh[base + i] = h[i]; pkl[base + i] = l[i]; }
}

// ---------------- MFMA GEMM (bf16x4 split), fp16 A rows ----------------
// mode 0: bias + two-pass LN (*gamma+beta) + ReLU -> fp16 out[row][col]
// mode 1: bias + ReLU, dot w2 (gamma slot) + b2 (beta slot) -> fp32 logits out[row]
__global__ __launch_bounds__(256) void gemm_mfma(const _Float16* __restrict__ A,
                                                 const short* __restrict__ Bh,
                                                 const short* __restrict__ Bl,
                                                 const float* __restrict__ bias,
                                                 const float* __restrict__ gamma,
                                                 const float* __restrict__ beta,
                                                 void* __restrict__ outraw,
                                                 int mode, int nrows) {
    int t = threadIdx.x;
    int wave = t >> 6, lane = t & 63;
    int lrow = lane & 15, lk = lane >> 4;
    int rowb = blockIdx.x * 64 + wave * 16;

    f32x4 acc[8];
#pragma unroll
    for (int cf = 0; cf < 8; ++cf) acc[cf] = (f32x4){0.f, 0.f, 0.f, 0.f};

    const _Float16* arow = A + (size_t)(rowb + lrow) * HDIM;

#pragma unroll
    for (int ks = 0; ks < 4; ++ks) {
        h16x8 a = *(const h16x8*)(arow + ks * 32 + lk * 8);
        bf16x8 ah, al;
#pragma unroll
        for (int i = 0; i < 8; ++i) {
            short hh, ll;
            bsplit((float)a[i], hh, ll);
            ah[i] = hh; al[i] = ll;
        }
        const short* bhp = Bh + (size_t)(ks * 8) * 512 + (size_t)lane * 8;
        const short* blp = Bl + (size_t)(ks * 8) * 512 + (size_t)lane * 8;
#pragma unroll
        for (int cf = 0; cf < 8; ++cf) {
            bf16x8 bh = *(const bf16x8*)(bhp + (size_t)cf * 512);
            bf16x8 bl = *(const bf16x8*)(blp + (size_t)cf * 512);
            acc[cf] = __builtin_amdgcn_mfma_f32_16x16x32_bf16(ah, bh, acc[cf], 0, 0, 0);
            acc[cf] = __builtin_amdgcn_mfma_f32_16x16x32_bf16(ah, bl, acc[cf], 0, 0, 0);
            acc[cf] = __builtin_amdgcn_mfma_f32_16x16x32_bf16(al, bh, acc[cf], 0, 0, 0);
            acc[cf] = __builtin_amdgcn_mfma_f32_16x16x32_bf16(al, bl, acc[cf], 0, 0, 0);
        }
    }

    // C/D layout: col = cf*16 + lrow, local row = lk*4 + r
    float bias_v[8];
#pragma unroll
    for (int cf = 0; cf < 8; ++cf) bias_v[cf] = bias[cf * 16 + lrow];

    if (mode == 0) {
        _Float16* out = (_Float16*)outraw;
        float gam[8], bet[8];
#pragma unroll
        for (int cf = 0; cf < 8; ++cf) {
            gam[cf] = gamma[cf * 16 + lrow];
            bet[cf] = beta[cf * 16 + lrow];
        }
#pragma unroll
        for (int r = 0; r < 4; ++r) {
            float vv[8];
            float s1 = 0.f;
#pragma unroll
            for (int cf = 0; cf < 8; ++cf) {
                vv[cf] = acc[cf][r] + bias_v[cf];
                s1 += vv[cf];
            }
#pragma unroll
            for (int m = 1; m <= 8; m <<= 1) s1 += __shfl_xor(s1, m);
            float mean = s1 * (1.0f / 128.0f);
            float s2 = 0.f;
            float cc[8];
#pragma unroll
            for (int cf = 0; cf < 8; ++cf) {
                cc[cf] = vv[cf] - mean;
                s2 += cc[cf] * cc[cf];
            }
#pragma unroll
            for (int m = 1; m <= 8; m <<= 1) s2 += __shfl_xor(s2, m);
            float var = s2 * (1.0f / 128.0f);
            float rs = rsqrtf(var + EPS);
            int row = rowb + lk * 4 + r;
            if (row < nrows) {
#pragma unroll
                for (int cf = 0; cf < 8; ++cf) {
                    float y = cc[cf] * rs * gam[cf] + bet[cf];
                    out[(size_t)row * HDIM + cf * 16 + lrow] = (_Float16)(y > 0.f ? y : 0.f);
                }
            }
        }
    } else {
        float* out = (float*)outraw;
        float w2v[8];
#pragma unroll
        for (int cf = 0; cf < 8; ++cf) w2v[cf] = gamma[cf * 16 + lrow];
        float b2 = beta[0];
#pragma unroll
        for (int r = 0; r < 4; ++r) {
            float part = 0.f;
#pragma unroll
            for (int cf = 0; cf < 8; ++cf) {
                float y = acc[cf][r] + bias_v[cf];
                y = y > 0.f ? y : 0.f;
                part += y * w2v[cf];
            }
#pragma unroll
            for (int m = 1; m <= 8; m <<= 1) part += __shfl_xor(part, m);
            int row = rowb + lk * 4 + r;
            if (row < nrows && lrow == 0) out[row] = part + b2;
        }
    }
}

extern "C" void kernel_launch(void* const* d_in, const int* in_sizes, int n_in,
                              void* d_out, int out_size, void* d_ws, size_t ws_size,
                              hipStream_t stream) {
    (void)in_sizes; (void)n_in; (void)out_size; (void)ws_size;
    const float* x   = (const float*)d_in[0];
    const int*   ei  = (const int*)d_in[1];
    const float* W0  = (const float*)d_in[2];
    const float* b0  = (const float*)d_in[3];
    const float* g0  = (const float*)d_in[4];
    const float* be0 = (const float*)d_in[5];
    const float* W1  = (const float*)d_in[6];
    const float* b1  = (const float*)d_in[7];
    const float* g1  = (const float*)d_in[8];
    const float* be1 = (const float*)d_in[9];
    const float* W2  = (const float*)d_in[10];
    const float* b2  = (const float*)d_in[11];
    const float* g2  = (const float*)d_in[12];
    const float* be2 = (const float*)d_in[13];
    const float* hW1 = (const float*)d_in[14];
    const float* hb1 = (const float*)d_in[15];
    const float* hW2 = (const float*)d_in[16];
    const float* hb2 = (const float*)d_in[17];
    float* out = (float*)d_out;

    char* w = (char*)d_ws;
    size_t off = 0;
    auto alloc = [&](size_t bytes) -> void* {
        void* p = w + off;
        off += (bytes + 255) & ~(size_t)255;
        return p;
    };
    float*     dinv  = (float*)alloc((size_t)N_NODES * 4);
    int*       deg   = (int*)alloc((size_t)N_NODES * 4);
    int*       rowst = (int*)alloc((size_t)(N_NODES + 1) * 4);
    int*       slot  = (int*)alloc((size_t)N_EDGES * 4);
    unsigned*  ecsr  = (unsigned*)alloc((size_t)(N_EDGES + 16) * 4);
    int*       bsum  = (int*)alloc(256 * 4);
    int*       boff  = (int*)alloc(256 * 4);
    int*       flag  = (int*)alloc(256);
    _Float16*  hagg  = (_Float16*)alloc((size_t)N_NODES * HDIM * 2);
    _Float16*  xh    = (_Float16*)alloc((size_t)N_NODES * HDIM * 2);
    _Float16*  hA    = (_Float16*)alloc((size_t)N_NODES * HDIM * 2);
    _Float16*  hB    = (_Float16*)alloc((size_t)N_NODES * HDIM * 2);
    short*     pkh   = (short*)alloc((size_t)4 * 16384 * 2);
    short*     pkl   = (short*)alloc((size_t)4 * 16384 * 2);

    hipMemsetAsync(deg, 0, (size_t)N_NODES * 4, stream);

    detect_kernel<<<1, 256, 0, stream>>>(ei, flag);
    cvt_x<<<(N_NODES * 32 + 255) / 256, 256, 0, stream>>>(x, xh);
    deg_kernel<<<(N_EDGES + 255) / 256, 256, 0, stream>>>(ei, flag, deg, slot);
    int nb = (N_NODES + 255) / 256; // 196
    block_sum<<<nb, 256, 0, stream>>>(deg, bsum, dinv);
    scan_bsums<<<1, 256, 0, stream>>>(bsum, boff, nb);
    scan_block<<<nb, 256, 0, stream>>>(deg, boff, rowst);
    scatter_kernel<<<(N_EDGES + 255) / 256, 256, 0, stream>>>(ei, flag, rowst, dinv, slot, ecsr);

    dim3 pg(8, 4);
    pack_w<<<pg, 256, 0, stream>>>(W0, W1, W2, hW1, pkh, pkl);

    int nab = (N_NODES + 7) / 8;   // 6250
    int ngb = (N_NODES + 63) / 64; // 782
    // layer 0: xh -> hagg -> hA
    agg_kernel<<<nab, 256, 0, stream>>>(xh, dinv, rowst, ecsr, hagg);
    gemm_mfma<<<ngb, 256, 0, stream>>>(hagg, pkh, pkl, b0, g0, be0, hA, 0, N_NODES);
    // layer 1: hA -> hagg -> hB
    agg_kernel<<<nab, 256, 0, stream>>>(hA, dinv, rowst, ecsr, hagg);
    gemm_mfma<<<ngb, 256, 0, stream>>>(hagg, pkh + (size_t)16384, pkl + (size_t)16384,
                                       b1, g1, be1, hB, 0, N_NODES);
    // layer 2: hB -> hagg -> hA
    agg_kernel<<<nab, 256, 0, stream>>>(hB, dinv, rowst, ecsr, hagg);
    gemm_mfma<<<ngb, 256, 0, stream>>>(hagg, pkh + (size_t)2 * 16384, pkl + (size_t)2 * 16384,
                                       b2, g2, be2, hA, 0, N_NODES);
    // fused head: ReLU(hA @ hW1 + hb1) @ hW2 + hb2 -> logits
    gemm_mfma<<<ngb, 256, 0, stream>>>(hA, pkh + (size_t)3 * 16384, pkl + (size_t)3 * 16384,
                                       hb1, hW2, hb2, out, 1, N_NODES);
}

// Round 8
// 201.733 us; speedup vs baseline: 1.4445x; 1.0143x over previous
//
#include <hip/hip_runtime.h>
#include <hip/hip_fp16.h>

#define N_NODES 50000
#define N_EDGES 600000
#define HDIM 128
#define EPS 1e-5f

typedef __attribute__((ext_vector_type(8))) short bf16x8;
typedef __attribute__((ext_vector_type(4))) float f32x4;
typedef __attribute__((ext_vector_type(4))) _Float16 h16x4;
typedef __attribute__((ext_vector_type(8))) _Float16 h16x8;

// ---------------- edge_index dtype detection (int32 vs int64) ----------------
__global__ void detect_kernel(const int* __restrict__ ei, int* __restrict__ flag) {
    __shared__ int nonzero;
    if (threadIdx.x == 0) nonzero = 0;
    __syncthreads();
    int acc = 0;
    for (int i = threadIdx.x; i < 1024; i += blockDim.x)
        acc |= ei[2 * i + 1];
    if (acc) atomicOr(&nonzero, 1);
    __syncthreads();
    if (threadIdx.x == 0) *flag = (nonzero == 0) ? 1 : 0;
}

__device__ __forceinline__ int load_idx(const int* __restrict__ ei, int pos, int f) {
    return f ? ei[2 * pos] : ei[pos];
}

// ---------------- x fp32 -> fp16 ----------------
__global__ void cvt_x(const float* __restrict__ x, _Float16* __restrict__ xh) {
    int idx = blockIdx.x * 256 + threadIdx.x; // one float4 per thread
    if (idx >= N_NODES * 32) return;
    float4 v = ((const float4*)x)[idx];
    h16x4 o;
    o[0] = (_Float16)v.x; o[1] = (_Float16)v.y; o[2] = (_Float16)v.z; o[3] = (_Float16)v.w;
    ((h16x4*)xh)[idx] = o;
}

// ---------------- degree pass: also assign within-row slot ----------------
__global__ void deg_kernel(const int* __restrict__ ei, const int* __restrict__ flag,
                           int* __restrict__ deg, int* __restrict__ slot) {
    int e = blockIdx.x * blockDim.x + threadIdx.x;
    if (e >= N_EDGES) return;
    int f = *flag;
    int d = load_idx(ei, N_EDGES + e, f);
    slot[e] = atomicAdd(&deg[d], 1);
}

// block_sum + dinv fused
__global__ void block_sum(const int* __restrict__ deg, int* __restrict__ bsum,
                          float* __restrict__ dinv) {
    __shared__ int sm[256];
    int i = blockIdx.x * 256 + threadIdx.x;
    int d = (i < N_NODES) ? deg[i] : 0;
    if (i < N_NODES) dinv[i] = rsqrtf((float)d + 1.0f); // +1 self-loop
    sm[threadIdx.x] = d;
    __syncthreads();
    for (int s = 128; s > 0; s >>= 1) {
        if (threadIdx.x < s) sm[threadIdx.x] += sm[threadIdx.x + s];
        __syncthreads();
    }
    if (threadIdx.x == 0) bsum[blockIdx.x] = sm[0];
}

__global__ void scan_bsums(const int* __restrict__ bsum, int* __restrict__ boff, int nb) {
    __shared__ int sm[256];
    int t = threadIdx.x;
    int v = (t < nb) ? bsum[t] : 0;
    sm[t] = v;
    __syncthreads();
    for (int s = 1; s < 256; s <<= 1) {
        int add = (t >= s) ? sm[t - s] : 0;
        __syncthreads();
        sm[t] += add;
        __syncthreads();
    }
    if (t < nb) boff[t] = sm[t] - v; // exclusive
}

__global__ void scan_block(const int* __restrict__ deg, const int* __restrict__ boff,
                           int* __restrict__ rowst) {
    __shared__ int sm[256];
    int t = threadIdx.x;
    int i = blockIdx.x * 256 + t;
    int v = (i < N_NODES) ? deg[i] : 0;
    sm[t] = v;
    __syncthreads();
    for (int s = 1; s < 256; s <<= 1) {
        int add = (t >= s) ? sm[t - s] : 0;
        __syncthreads();
        sm[t] += add;
        __syncthreads();
    }
    int excl = boff[blockIdx.x] + sm[t] - v;
    if (i < N_NODES) rowst[i] = excl;
    if (i == N_NODES - 1) rowst[N_NODES] = excl + v;
}

// scatter: 4B packed store per edge {fp16(dinv[src]) << 16 | src}
__global__ void scatter_kernel(const int* __restrict__ ei, const int* __restrict__ flag,
                               const int* __restrict__ rowst, const float* __restrict__ dinv,
                               const int* __restrict__ slot, unsigned* __restrict__ ecsr) {
    int e = blockIdx.x * blockDim.x + threadIdx.x;
    if (e >= N_EDGES) return;
    if (e < 16) ecsr[N_EDGES + e] = 0u;
    int f = *flag;
    int s = load_idx(ei, e, f);
    int d = load_idx(ei, N_EDGES + e, f);
    int pos = rowst[d] + slot[e];
    _Float16 wv = (_Float16)dinv[s];
    unsigned wb = (unsigned)__builtin_bit_cast(unsigned short, wv);
    ecsr[pos] = (wb << 16) | (unsigned)s;
}

__device__ __forceinline__ float unpack_w(unsigned p) {
    unsigned short b = (unsigned short)(p >> 16);
    return (float)__builtin_bit_cast(_Float16, b);
}

// ---------------- aggregation: 4 nodes/wave (16 lanes x 16B), 4-deep -> 16 gathers in flight ----------------
__global__ __launch_bounds__(256) void agg_kernel(const _Float16* __restrict__ h,
                                                  const float* __restrict__ dinv,
                                                  const int* __restrict__ rowst,
                                                  const unsigned* __restrict__ ecsr,
                                                  _Float16* __restrict__ out) {
    int node = blockIdx.x * 16 + (threadIdx.x >> 4);
    int sub = threadIdx.x & 15;
    if (node >= N_NODES) return;
    const h16x8* h8 = (const h16x8*)h;
    float dd = dinv[node];
    h16x8 v = h8[(size_t)node * 16 + sub];
    float acc[8];
#pragma unroll
    for (int i = 0; i < 8; ++i) acc[i] = dd * (float)v[i]; // self (×dd below)
    int e1 = rowst[node + 1];
    for (int e = rowst[node]; e < e1; e += 4) {
        unsigned p0 = ecsr[e];
        unsigned p1 = ecsr[e + 1];
        unsigned p2 = ecsr[e + 2];
        unsigned p3 = ecsr[e + 3];
        int s0 = p0 & 0xFFFFu;
        float w0 = unpack_w(p0);
        int s1 = (e + 1 < e1) ? (int)(p1 & 0xFFFFu) : s0;
        float w1 = (e + 1 < e1) ? unpack_w(p1) : 0.f;
        int s2 = (e + 2 < e1) ? (int)(p2 & 0xFFFFu) : s0;
        float w2 = (e + 2 < e1) ? unpack_w(p2) : 0.f;
        int s3 = (e + 3 < e1) ? (int)(p3 & 0xFFFFu) : s0;
        float w3 = (e + 3 < e1) ? unpack_w(p3) : 0.f;
        h16x8 u0 = h8[(size_t)s0 * 16 + sub];
        h16x8 u1 = h8[(size_t)s1 * 16 + sub];
        h16x8 u2 = h8[(size_t)s2 * 16 + sub];
        h16x8 u3 = h8[(size_t)s3 * 16 + sub];
#pragma unroll
        for (int i = 0; i < 8; ++i) {
            acc[i] += w0 * (float)u0[i];
            acc[i] += w1 * (float)u1[i];
            acc[i] += w2 * (float)u2[i];
            acc[i] += w3 * (float)u3[i];
        }
    }
    h16x8 r;
#pragma unroll
    for (int i = 0; i < 8; ++i) r[i] = (_Float16)(acc[i] * dd);
    ((h16x8*)out)[(size_t)node * 16 + sub] = r;
}

// ---------------- bf16 hi/lo split ----------------
__device__ __forceinline__ void bsplit(float a, short& hi, short& lo) {
    unsigned u = __float_as_uint(a);
    unsigned r = (u + 0x7FFFu + ((u >> 16) & 1u)) & 0xFFFF0000u; // RNE
    hi = (short)(r >> 16);
    float l = a - __uint_as_float(r);
    unsigned ul = __float_as_uint(l);
    unsigned rl = ul + 0x7FFFu + ((ul >> 16) & 1u);
    lo = (short)(rl >> 16);
}

// ---------------- pack W [128][128] fp32 -> per-lane MFMA B-fragments (hi/lo bf16) ----------------
__global__ void pack_w(const float* __restrict__ W0, const float* __restrict__ W1,
                       const float* __restrict__ W2, const float* __restrict__ W3,
                       short* __restrict__ pkh, short* __restrict__ pkl) {
    const float* W = (blockIdx.y == 0) ? W0 : (blockIdx.y == 1) ? W1
                   : (blockIdx.y == 2) ? W2 : W3;
    int idx = blockIdx.x * 256 + threadIdx.x; // 0..2047
    int lane = idx & 63;
    int cf = (idx >> 6) & 7;
    int ks = idx >> 9;
    int col = cf * 16 + (lane & 15);
    int k0 = ks * 32 + (lane >> 4) * 8;
    short h[8], l[8];
#pragma unroll
    for (int i = 0; i < 8; ++i) bsplit(W[(size_t)(k0 + i) * HDIM + col], h[i], l[i]);
    size_t base = (size_t)blockIdx.y * 16384 + (size_t)idx * 8;
#pragma unroll
    for (int i = 0; i < 8; ++i) { pkh[base + i] = h[i]; pkl[base + i] = l[i]; }
}

// ---------------- MFMA GEMM (bf16x4 split), fp16 A rows ----------------
// mode 0: bias + two-pass LN (*gamma+beta) + ReLU -> fp16 out[row][col]
// mode 1: bias + ReLU, dot w2 (gamma slot) + b2 (beta slot) -> fp32 logits out[row]
__global__ __launch_bounds__(256) void gemm_mfma(const _Float16* __restrict__ A,
                                                 const short* __restrict__ Bh,
                                                 const short* __restrict__ Bl,
                                                 const float* __restrict__ bias,
                                                 const float* __restrict__ gamma,
                                                 const float* __restrict__ beta,
                                                 void* __restrict__ outraw,
                                                 int mode, int nrows) {
    int t = threadIdx.x;
    int wave = t >> 6, lane = t & 63;
    int lrow = lane & 15, lk = lane >> 4;
    int rowb = blockIdx.x * 64 + wave * 16;

    f32x4 acc[8];
#pragma unroll
    for (int cf = 0; cf < 8; ++cf) acc[cf] = (f32x4){0.f, 0.f, 0.f, 0.f};

    const _Float16* arow = A + (size_t)(rowb + lrow) * HDIM;

#pragma unroll
    for (int ks = 0; ks < 4; ++ks) {
        h16x8 a = *(const h16x8*)(arow + ks * 32 + lk * 8);
        bf16x8 ah, al;
#pragma unroll
        for (int i = 0; i < 8; ++i) {
            short hh, ll;
            bsplit((float)a[i], hh, ll);
            ah[i] = hh; al[i] = ll;
        }
        const short* bhp = Bh + (size_t)(ks * 8) * 512 + (size_t)lane * 8;
        const short* blp = Bl + (size_t)(ks * 8) * 512 + (size_t)lane * 8;
#pragma unroll
        for (int cf = 0; cf < 8; ++cf) {
            bf16x8 bh = *(const bf16x8*)(bhp + (size_t)cf * 512);
            bf16x8 bl = *(const bf16x8*)(blp + (size_t)cf * 512);
            acc[cf] = __builtin_amdgcn_mfma_f32_16x16x32_bf16(ah, bh, acc[cf], 0, 0, 0);
            acc[cf] = __builtin_amdgcn_mfma_f32_16x16x32_bf16(ah, bl, acc[cf], 0, 0, 0);
            acc[cf] = __builtin_amdgcn_mfma_f32_16x16x32_bf16(al, bh, acc[cf], 0, 0, 0);
            acc[cf] = __builtin_amdgcn_mfma_f32_16x16x32_bf16(al, bl, acc[cf], 0, 0, 0);
        }
    }

    // C/D layout: col = cf*16 + lrow, local row = lk*4 + r
    float bias_v[8];
#pragma unroll
    for (int cf = 0; cf < 8; ++cf) bias_v[cf] = bias[cf * 16 + lrow];

    if (mode == 0) {
        _Float16* out = (_Float16*)outraw;
        float gam[8], bet[8];
#pragma unroll
        for (int cf = 0; cf < 8; ++cf) {
            gam[cf] = gamma[cf * 16 + lrow];
            bet[cf] = beta[cf * 16 + lrow];
        }
#pragma unroll
        for (int r = 0; r < 4; ++r) {
            float vv[8];
            float s1 = 0.f;
#pragma unroll
            for (int cf = 0; cf < 8; ++cf) {
                vv[cf] = acc[cf][r] + bias_v[cf];
                s1 += vv[cf];
            }
#pragma unroll
            for (int m = 1; m <= 8; m <<= 1) s1 += __shfl_xor(s1, m);
            float mean = s1 * (1.0f / 128.0f);
            float s2 = 0.f;
            float cc[8];
#pragma unroll
            for (int cf = 0; cf < 8; ++cf) {
                cc[cf] = vv[cf] - mean;
                s2 += cc[cf] * cc[cf];
            }
#pragma unroll
            for (int m = 1; m <= 8; m <<= 1) s2 += __shfl_xor(s2, m);
            float var = s2 * (1.0f / 128.0f);
            float rs = rsqrtf(var + EPS);
            int row = rowb + lk * 4 + r;
            if (row < nrows) {
#pragma unroll
                for (int cf = 0; cf < 8; ++cf) {
                    float y = cc[cf] * rs * gam[cf] + bet[cf];
                    out[(size_t)row * HDIM + cf * 16 + lrow] = (_Float16)(y > 0.f ? y : 0.f);
                }
            }
        }
    } else {
        float* out = (float*)outraw;
        float w2v[8];
#pragma unroll
        for (int cf = 0; cf < 8; ++cf) w2v[cf] = gamma[cf * 16 + lrow];
        float b2 = beta[0];
#pragma unroll
        for (int r = 0; r < 4; ++r) {
            float part = 0.f;
#pragma unroll
            for (int cf = 0; cf < 8; ++cf) {
                float y = acc[cf][r] + bias_v[cf];
                y = y > 0.f ? y : 0.f;
                part += y * w2v[cf];
            }
#pragma unroll
            for (int m = 1; m <= 8; m <<= 1) part += __shfl_xor(part, m);
            int row = rowb + lk * 4 + r;
            if (row < nrows && lrow == 0) out[row] = part + b2;
        }
    }
}

extern "C" void kernel_launch(void* const* d_in, const int* in_sizes, int n_in,
                              void* d_out, int out_size, void* d_ws, size_t ws_size,
                              hipStream_t stream) {
    (void)in_sizes; (void)n_in; (void)out_size; (void)ws_size;
    const float* x   = (const float*)d_in[0];
    const int*   ei  = (const int*)d_in[1];
    const float* W0  = (const float*)d_in[2];
    const float* b0  = (const float*)d_in[3];
    const float* g0  = (const float*)d_in[4];
    const float* be0 = (const float*)d_in[5];
    const float* W1  = (const float*)d_in[6];
    const float* b1  = (const float*)d_in[7];
    const float* g1  = (const float*)d_in[8];
    const float* be1 = (const float*)d_in[9];
    const float* W2  = (const float*)d_in[10];
    const float* b2  = (const float*)d_in[11];
    const float* g2  = (const float*)d_in[12];
    const float* be2 = (const float*)d_in[13];
    const float* hW1 = (const float*)d_in[14];
    const float* hb1 = (const float*)d_in[15];
    const float* hW2 = (const float*)d_in[16];
    const float* hb2 = (const float*)d_in[17];
    float* out = (float*)d_out;

    char* w = (char*)d_ws;
    size_t off = 0;
    auto alloc = [&](size_t bytes) -> void* {
        void* p = w + off;
        off += (bytes + 255) & ~(size_t)255;
        return p;
    };
    float*     dinv  = (float*)alloc((size_t)N_NODES * 4);
    int*       deg   = (int*)alloc((size_t)N_NODES * 4);
    int*       rowst = (int*)alloc((size_t)(N_NODES + 1) * 4);
    int*       slot  = (int*)alloc((size_t)N_EDGES * 4);
    unsigned*  ecsr  = (unsigned*)alloc((size_t)(N_EDGES + 16) * 4);
    int*       bsum  = (int*)alloc(256 * 4);
    int*       boff  = (int*)alloc(256 * 4);
    int*       flag  = (int*)alloc(256);
    _Float16*  hagg  = (_Float16*)alloc((size_t)N_NODES * HDIM * 2);
    _Float16*  xh    = (_Float16*)alloc((size_t)N_NODES * HDIM * 2);
    _Float16*  hA    = (_Float16*)alloc((size_t)N_NODES * HDIM * 2);
    _Float16*  hB    = (_Float16*)alloc((size_t)N_NODES * HDIM * 2);
    short*     pkh   = (short*)alloc((size_t)4 * 16384 * 2);
    short*     pkl   = (short*)alloc((size_t)4 * 16384 * 2);

    hipMemsetAsync(deg, 0, (size_t)N_NODES * 4, stream);

    detect_kernel<<<1, 256, 0, stream>>>(ei, flag);
    cvt_x<<<(N_NODES * 32 + 255) / 256, 256, 0, stream>>>(x, xh);
    deg_kernel<<<(N_EDGES + 255) / 256, 256, 0, stream>>>(ei, flag, deg, slot);
    int nb = (N_NODES + 255) / 256; // 196
    block_sum<<<nb, 256, 0, stream>>>(deg, bsum, dinv);
    scan_bsums<<<1, 256, 0, stream>>>(bsum, boff, nb);
    scan_block<<<nb, 256, 0, stream>>>(deg, boff, rowst);
    scatter_kernel<<<(N_EDGES + 255) / 256, 256, 0, stream>>>(ei, flag, rowst, dinv, slot, ecsr);

    dim3 pg(8, 4);
    pack_w<<<pg, 256, 0, stream>>>(W0, W1, W2, hW1, pkh, pkl);

    int nab = (N_NODES + 15) / 16; // 3125
    int ngb = (N_NODES + 63) / 64; // 782
    // layer 0: xh -> hagg -> hA
    agg_kernel<<<nab, 256, 0, stream>>>(xh, dinv, rowst, ecsr, hagg);
    gemm_mfma<<<ngb, 256, 0, stream>>>(hagg, pkh, pkl, b0, g0, be0, hA, 0, N_NODES);
    // layer 1: hA -> hagg -> hB
    agg_kernel<<<nab, 256, 0, stream>>>(hA, dinv, rowst, ecsr, hagg);
    gemm_mfma<<<ngb, 256, 0, stream>>>(hagg, pkh + (size_t)16384, pkl + (size_t)16384,
                                       b1, g1, be1, hB, 0, N_NODES);
    // layer 2: hB -> hagg -> hA
    agg_kernel<<<nab, 256, 0, stream>>>(hB, dinv, rowst, ecsr, hagg);
    gemm_mfma<<<ngb, 256, 0, stream>>>(hagg, pkh + (size_t)2 * 16384, pkl + (size_t)2 * 16384,
                                       b2, g2, be2, hA, 0, N_NODES);
    // fused head: ReLU(hA @ hW1 + hb1) @ hW2 + hb2 -> logits
    gemm_mfma<<<ngb, 256, 0, stream>>>(hA, pkh + (size_t)3 * 16384, pkl + (size_t)3 * 16384,
                                       hb1, hW2, hb2, out, 1, N_NODES);
}

// Round 9
// 190.488 us; speedup vs baseline: 1.5298x; 1.0590x over previous
//
#include <hip/hip_runtime.h>
#include <hip/hip_fp16.h>

#define N_NODES 50000
#define N_EDGES 600000
#define HDIM 128
#define EPS 1e-5f

typedef __attribute__((ext_vector_type(4))) float f32x4;
typedef __attribute__((ext_vector_type(4))) _Float16 h16x4;
typedef __attribute__((ext_vector_type(8))) _Float16 h16x8;

#define CVT_BLKS 6250            // N_NODES*32 float4 / 256
#define DEG_BLKS ((N_EDGES + 255) / 256)
#define PACK_BLKS 32             // 4 weights x 8 blocks

// ---------------- edge_index dtype detection (int32 vs int64) ----------------
__global__ void detect_kernel(const int* __restrict__ ei, int* __restrict__ flag) {
    __shared__ int nonzero;
    if (threadIdx.x == 0) nonzero = 0;
    __syncthreads();
    int acc = 0;
    for (int i = threadIdx.x; i < 1024; i += blockDim.x)
        acc |= ei[2 * i + 1];
    if (acc) atomicOr(&nonzero, 1);
    __syncthreads();
    if (threadIdx.x == 0) *flag = (nonzero == 0) ? 1 : 0;
}

__device__ __forceinline__ int load_idx(const int* __restrict__ ei, int pos, int f) {
    return f ? ei[2 * pos] : ei[pos];
}

// ---------------- f16 hi/lo split ----------------
__device__ __forceinline__ void hsplit(float a, _Float16& hi, _Float16& lo) {
    _Float16 h = (_Float16)a;           // RNE
    hi = h;
    lo = (_Float16)(a - (float)h);
}

// ---------------- fused prep: cvt_x | deg+slot | pack_w ----------------
// pack layout: frag index = ((ks*8 + cf)*64 + lane)*8;
// lane holds B[ks*32 + (lane>>4)*8 + i][cf*16 + (lane&15)]
__global__ void prep_kernel(const float* __restrict__ x, _Float16* __restrict__ xh,
                            const int* __restrict__ ei, const int* __restrict__ flag,
                            int* __restrict__ deg, int* __restrict__ slot,
                            const float* __restrict__ W0, const float* __restrict__ W1,
                            const float* __restrict__ W2, const float* __restrict__ W3,
                            _Float16* __restrict__ pkh, _Float16* __restrict__ pkl) {
    int b = blockIdx.x;
    if (b < CVT_BLKS) {
        int idx = b * 256 + threadIdx.x;
        if (idx < N_NODES * 32) {
            float4 v = ((const float4*)x)[idx];
            h16x4 o;
            o[0] = (_Float16)v.x; o[1] = (_Float16)v.y;
            o[2] = (_Float16)v.z; o[3] = (_Float16)v.w;
            ((h16x4*)xh)[idx] = o;
        }
    } else if (b < CVT_BLKS + DEG_BLKS) {
        int e = (b - CVT_BLKS) * 256 + threadIdx.x;
        if (e < N_EDGES) {
            int f = *flag;
            int d = load_idx(ei, N_EDGES + e, f);
            slot[e] = atomicAdd(&deg[d], 1);
        }
    } else {
        int pb = b - CVT_BLKS - DEG_BLKS;   // 0..31
        int wsel = pb >> 3;
        const float* W = (wsel == 0) ? W0 : (wsel == 1) ? W1 : (wsel == 2) ? W2 : W3;
        int idx = (pb & 7) * 256 + threadIdx.x; // 0..2047
        int lane = idx & 63;
        int cf = (idx >> 6) & 7;
        int ks = idx >> 9;
        int col = cf * 16 + (lane & 15);
        int k0 = ks * 32 + (lane >> 4) * 8;
        _Float16 h[8], l[8];
#pragma unroll
        for (int i = 0; i < 8; ++i) hsplit(W[(size_t)(k0 + i) * HDIM + col], h[i], l[i]);
        size_t base = (size_t)wsel * 16384 + (size_t)idx * 8;
#pragma unroll
        for (int i = 0; i < 8; ++i) { pkh[base + i] = h[i]; pkl[base + i] = l[i]; }
    }
}

// block_sum + dinv fused
__global__ void block_sum(const int* __restrict__ deg, int* __restrict__ bsum,
                          float* __restrict__ dinv) {
    __shared__ int sm[256];
    int i = blockIdx.x * 256 + threadIdx.x;
    int d = (i < N_NODES) ? deg[i] : 0;
    if (i < N_NODES) dinv[i] = rsqrtf((float)d + 1.0f); // +1 self-loop
    sm[threadIdx.x] = d;
    __syncthreads();
    for (int s = 128; s > 0; s >>= 1) {
        if (threadIdx.x < s) sm[threadIdx.x] += sm[threadIdx.x + s];
        __syncthreads();
    }
    if (threadIdx.x == 0) bsum[blockIdx.x] = sm[0];
}

__global__ void scan_bsums(const int* __restrict__ bsum, int* __restrict__ boff, int nb) {
    __shared__ int sm[256];
    int t = threadIdx.x;
    int v = (t < nb) ? bsum[t] : 0;
    sm[t] = v;
    __syncthreads();
    for (int s = 1; s < 256; s <<= 1) {
        int add = (t >= s) ? sm[t - s] : 0;
        __syncthreads();
        sm[t] += add;
        __syncthreads();
    }
    if (t < nb) boff[t] = sm[t] - v; // exclusive
}

__global__ void scan_block(const int* __restrict__ deg, const int* __restrict__ boff,
                           int* __restrict__ rowst) {
    __shared__ int sm[256];
    int t = threadIdx.x;
    int i = blockIdx.x * 256 + t;
    int v = (i < N_NODES) ? deg[i] : 0;
    sm[t] = v;
    __syncthreads();
    for (int s = 1; s < 256; s <<= 1) {
        int add = (t >= s) ? sm[t - s] : 0;
        __syncthreads();
        sm[t] += add;
        __syncthreads();
    }
    int excl = boff[blockIdx.x] + sm[t] - v;
    if (i < N_NODES) rowst[i] = excl;
    if (i == N_NODES - 1) rowst[N_NODES] = excl + v;
}

// scatter: 4B packed store per edge {fp16(dinv[src]) << 16 | src}
__global__ void scatter_kernel(const int* __restrict__ ei, const int* __restrict__ flag,
                               const int* __restrict__ rowst, const float* __restrict__ dinv,
                               const int* __restrict__ slot, unsigned* __restrict__ ecsr) {
    int e = blockIdx.x * blockDim.x + threadIdx.x;
    if (e >= N_EDGES) return;
    if (e < 16) ecsr[N_EDGES + e] = 0u;
    int f = *flag;
    int s = load_idx(ei, e, f);
    int d = load_idx(ei, N_EDGES + e, f);
    int pos = rowst[d] + slot[e];
    _Float16 wv = (_Float16)dinv[s];
    unsigned wb = (unsigned)__builtin_bit_cast(unsigned short, wv);
    ecsr[pos] = (wb << 16) | (unsigned)s;
}

__device__ __forceinline__ float unpack_w(unsigned p) {
    unsigned short b = (unsigned short)(p >> 16);
    return (float)__builtin_bit_cast(_Float16, b);
}

// ---------------- aggregation: 4 nodes/wave (16 lanes x 16B), 4-deep ----------------
__global__ __launch_bounds__(256) void agg_kernel(const _Float16* __restrict__ h,
                                                  const float* __restrict__ dinv,
                                                  const int* __restrict__ rowst,
                                                  const unsigned* __restrict__ ecsr,
                                                  _Float16* __restrict__ out) {
    int node = blockIdx.x * 16 + (threadIdx.x >> 4);
    int sub = threadIdx.x & 15;
    if (node >= N_NODES) return;
    const h16x8* h8 = (const h16x8*)h;
    float dd = dinv[node];
    h16x8 v = h8[(size_t)node * 16 + sub];
    float acc[8];
#pragma unroll
    for (int i = 0; i < 8; ++i) acc[i] = dd * (float)v[i]; // self (×dd below)
    int e1 = rowst[node + 1];
    for (int e = rowst[node]; e < e1; e += 4) {
        unsigned p0 = ecsr[e];
        unsigned p1 = ecsr[e + 1];
        unsigned p2 = ecsr[e + 2];
        unsigned p3 = ecsr[e + 3];
        int s0 = p0 & 0xFFFFu;
        float w0 = unpack_w(p0);
        int s1 = (e + 1 < e1) ? (int)(p1 & 0xFFFFu) : s0;
        float w1 = (e + 1 < e1) ? unpack_w(p1) : 0.f;
        int s2 = (e + 2 < e1) ? (int)(p2 & 0xFFFFu) : s0;
        float w2 = (e + 2 < e1) ? unpack_w(p2) : 0.f;
        int s3 = (e + 3 < e1) ? (int)(p3 & 0xFFFFu) : s0;
        float w3 = (e + 3 < e1) ? unpack_w(p3) : 0.f;
        h16x8 u0 = h8[(size_t)s0 * 16 + sub];
        h16x8 u1 = h8[(size_t)s1 * 16 + sub];
        h16x8 u2 = h8[(size_t)s2 * 16 + sub];
        h16x8 u3 = h8[(size_t)s3 * 16 + sub];
#pragma unroll
        for (int i = 0; i < 8; ++i) {
            acc[i] += w0 * (float)u0[i];
            acc[i] += w1 * (float)u1[i];
            acc[i] += w2 * (float)u2[i];
            acc[i] += w3 * (float)u3[i];
        }
    }
    h16x8 r;
#pragma unroll
    for (int i = 0; i < 8; ++i) r[i] = (_Float16)(acc[i] * dd);
    ((h16x8*)out)[(size_t)node * 16 + sub] = r;
}

// ---------------- MFMA GEMM: f16 A (exact), W split f16 hi/lo -> 2 MFMA/frag ----------------
// mode 0: bias + two-pass LN (*gamma+beta) + ReLU -> fp16 out[row][col]
// mode 1: bias + ReLU, dot w2 (gamma slot) + b2 (beta slot) -> fp32 logits out[row]
__global__ __launch_bounds__(256) void gemm_mfma(const _Float16* __restrict__ A,
                                                 const _Float16* __restrict__ Bh,
                                                 const _Float16* __restrict__ Bl,
                                                 const float* __restrict__ bias,
                                                 const float* __restrict__ gamma,
                                                 const float* __restrict__ beta,
                                                 void* __restrict__ outraw,
                                                 int mode, int nrows) {
    int t = threadIdx.x;
    int wave = t >> 6, lane = t & 63;
    int lrow = lane & 15, lk = lane >> 4;
    int rowb = blockIdx.x * 64 + wave * 16;

    f32x4 acc[8];
#pragma unroll
    for (int cf = 0; cf < 8; ++cf) acc[cf] = (f32x4){0.f, 0.f, 0.f, 0.f};

    const _Float16* arow = A + (size_t)(rowb + lrow) * HDIM;

#pragma unroll
    for (int ks = 0; ks < 4; ++ks) {
        h16x8 a = *(const h16x8*)(arow + ks * 32 + lk * 8); // exact f16 A fragment
        const _Float16* bhp = Bh + (size_t)(ks * 8) * 512 + (size_t)lane * 8;
        const _Float16* blp = Bl + (size_t)(ks * 8) * 512 + (size_t)lane * 8;
#pragma unroll
        for (int cf = 0; cf < 8; ++cf) {
            h16x8 bh = *(const h16x8*)(bhp + (size_t)cf * 512);
            h16x8 bl = *(const h16x8*)(blp + (size_t)cf * 512);
            acc[cf] = __builtin_amdgcn_mfma_f32_16x16x32_f16(a, bh, acc[cf], 0, 0, 0);
            acc[cf] = __builtin_amdgcn_mfma_f32_16x16x32_f16(a, bl, acc[cf], 0, 0, 0);
        }
    }

    // C/D layout: col = cf*16 + lrow, local row = lk*4 + r
    float bias_v[8];
#pragma unroll
    for (int cf = 0; cf < 8; ++cf) bias_v[cf] = bias[cf * 16 + lrow];

    if (mode == 0) {
        _Float16* out = (_Float16*)outraw;
        float gam[8], bet[8];
#pragma unroll
        for (int cf = 0; cf < 8; ++cf) {
            gam[cf] = gamma[cf * 16 + lrow];
            bet[cf] = beta[cf * 16 + lrow];
        }
#pragma unroll
        for (int r = 0; r < 4; ++r) {
            float vv[8];
            float s1 = 0.f;
#pragma unroll
            for (int cf = 0; cf < 8; ++cf) {
                vv[cf] = acc[cf][r] + bias_v[cf];
                s1 += vv[cf];
            }
#pragma unroll
            for (int m = 1; m <= 8; m <<= 1) s1 += __shfl_xor(s1, m);
            float mean = s1 * (1.0f / 128.0f);
            float s2 = 0.f;
            float cc[8];
#pragma unroll
            for (int cf = 0; cf < 8; ++cf) {
                cc[cf] = vv[cf] - mean;
                s2 += cc[cf] * cc[cf];
            }
#pragma unroll
            for (int m = 1; m <= 8; m <<= 1) s2 += __shfl_xor(s2, m);
            float var = s2 * (1.0f / 128.0f);
            float rs = rsqrtf(var + EPS);
            int row = rowb + lk * 4 + r;
            if (row < nrows) {
#pragma unroll
                for (int cf = 0; cf < 8; ++cf) {
                    float y = cc[cf] * rs * gam[cf] + bet[cf];
                    out[(size_t)row * HDIM + cf * 16 + lrow] = (_Float16)(y > 0.f ? y : 0.f);
                }
            }
        }
    } else {
        float* out = (float*)outraw;
        float w2v[8];
#pragma unroll
        for (int cf = 0; cf < 8; ++cf) w2v[cf] = gamma[cf * 16 + lrow];
        float b2 = beta[0];
#pragma unroll
        for (int r = 0; r < 4; ++r) {
            float part = 0.f;
#pragma unroll
            for (int cf = 0; cf < 8; ++cf) {
                float y = acc[cf][r] + bias_v[cf];
                y = y > 0.f ? y : 0.f;
                part += y * w2v[cf];
            }
#pragma unroll
            for (int m = 1; m <= 8; m <<= 1) part += __shfl_xor(part, m);
            int row = rowb + lk * 4 + r;
            if (row < nrows && lrow == 0) out[row] = part + b2;
        }
    }
}

extern "C" void kernel_launch(void* const* d_in, const int* in_sizes, int n_in,
                              void* d_out, int out_size, void* d_ws, size_t ws_size,
                              hipStream_t stream) {
    (void)in_sizes; (void)n_in; (void)out_size; (void)ws_size;
    const float* x   = (const float*)d_in[0];
    const int*   ei  = (const int*)d_in[1];
    const float* W0  = (const float*)d_in[2];
    const float* b0  = (const float*)d_in[3];
    const float* g0  = (const float*)d_in[4];
    const float* be0 = (const float*)d_in[5];
    const float* W1  = (const float*)d_in[6];
    const float* b1  = (const float*)d_in[7];
    const float* g1  = (const float*)d_in[8];
    const float* be1 = (const float*)d_in[9];
    const float* W2  = (const float*)d_in[10];
    const float* b2  = (const float*)d_in[11];
    const float* g2  = (const float*)d_in[12];
    const float* be2 = (const float*)d_in[13];
    const float* hW1 = (const float*)d_in[14];
    const float* hb1 = (const float*)d_in[15];
    const float* hW2 = (const float*)d_in[16];
    const float* hb2 = (const float*)d_in[17];
    float* out = (float*)d_out;

    char* w = (char*)d_ws;
    size_t off = 0;
    auto alloc = [&](size_t bytes) -> void* {
        void* p = w + off;
        off += (bytes + 255) & ~(size_t)255;
        return p;
    };
    float*     dinv  = (float*)alloc((size_t)N_NODES * 4);
    int*       deg   = (int*)alloc((size_t)N_NODES * 4);
    int*       rowst = (int*)alloc((size_t)(N_NODES + 1) * 4);
    int*       slot  = (int*)alloc((size_t)N_EDGES * 4);
    unsigned*  ecsr  = (unsigned*)alloc((size_t)(N_EDGES + 16) * 4);
    int*       bsum  = (int*)alloc(256 * 4);
    int*       boff  = (int*)alloc(256 * 4);
    int*       flag  = (int*)alloc(256);
    _Float16*  hagg  = (_Float16*)alloc((size_t)N_NODES * HDIM * 2);
    _Float16*  xh    = (_Float16*)alloc((size_t)N_NODES * HDIM * 2);
    _Float16*  hA    = (_Float16*)alloc((size_t)N_NODES * HDIM * 2);
    _Float16*  hB    = (_Float16*)alloc((size_t)N_NODES * HDIM * 2);
    _Float16*  pkh   = (_Float16*)alloc((size_t)4 * 16384 * 2);
    _Float16*  pkl   = (_Float16*)alloc((size_t)4 * 16384 * 2);

    hipMemsetAsync(deg, 0, (size_t)N_NODES * 4, stream);

    detect_kernel<<<1, 256, 0, stream>>>(ei, flag);
    prep_kernel<<<CVT_BLKS + DEG_BLKS + PACK_BLKS, 256, 0, stream>>>(
        x, xh, ei, flag, deg, slot, W0, W1, W2, hW1, pkh, pkl);
    int nb = (N_NODES + 255) / 256; // 196
    block_sum<<<nb, 256, 0, stream>>>(deg, bsum, dinv);
    scan_bsums<<<1, 256, 0, stream>>>(bsum, boff, nb);
    scan_block<<<nb, 256, 0, stream>>>(deg, boff, rowst);
    scatter_kernel<<<(N_EDGES + 255) / 256, 256, 0, stream>>>(ei, flag, rowst, dinv, slot, ecsr);

    int nab = (N_NODES + 15) / 16; // 3125
    int ngb = (N_NODES + 63) / 64; // 782
    // layer 0: xh -> hagg -> hA
    agg_kernel<<<nab, 256, 0, stream>>>(xh, dinv, rowst, ecsr, hagg);
    gemm_mfma<<<ngb, 256, 0, stream>>>(hagg, pkh, pkl, b0, g0, be0, hA, 0, N_NODES);
    // layer 1: hA -> hagg -> hB
    agg_kernel<<<nab, 256, 0, stream>>>(hA, dinv, rowst, ecsr, hagg);
    gemm_mfma<<<ngb, 256, 0, stream>>>(hagg, pkh + (size_t)16384, pkl + (size_t)16384,
                                       b1, g1, be1, hB, 0, N_NODES);
    // layer 2: hB -> hagg -> hA
    agg_kernel<<<nab, 256, 0, stream>>>(hB, dinv, rowst, ecsr, hagg);
    gemm_mfma<<<ngb, 256, 0, stream>>>(hagg, pkh + (size_t)2 * 16384, pkl + (size_t)2 * 16384,
                                       b2, g2, be2, hA, 0, N_NODES);
    // fused head: ReLU(hA @ hW1 + hb1) @ hW2 + hb2 -> logits
    gemm_mfma<<<ngb, 256, 0, stream>>>(hA, pkh + (size_t)3 * 16384, pkl + (size_t)3 * 16384,
                                       hb1, hW2, hb2, out, 1, N_NODES);
}

// Round 10
// 188.522 us; speedup vs baseline: 1.5457x; 1.0104x over previous
//
#include <hip/hip_runtime.h>
#include <hip/hip_fp16.h>

#define N_NODES 50000
#define N_EDGES 600000
#define HDIM 128
#define EPS 1e-5f
#define ELLW 64

typedef __attribute__((ext_vector_type(4))) float f32x4;
typedef __attribute__((ext_vector_type(4))) _Float16 h16x4;
typedef __attribute__((ext_vector_type(8))) _Float16 h16x8;

#define CVT_BLKS 6250                        // N_NODES*32 float4 / 256
#define EDGE_BLKS ((N_EDGES + 1023) / 1024)  // 4 edges per thread
#define PACK_BLKS 32                         // 4 weights x 8 blocks

// ---------------- edge_index dtype detection (int32 vs int64) ----------------
__global__ void detect_kernel(const int* __restrict__ ei, int* __restrict__ flag) {
    __shared__ int nonzero;
    if (threadIdx.x == 0) nonzero = 0;
    __syncthreads();
    int acc = 0;
    for (int i = threadIdx.x; i < 1024; i += blockDim.x)
        acc |= ei[2 * i + 1];
    if (acc) atomicOr(&nonzero, 1);
    __syncthreads();
    if (threadIdx.x == 0) *flag = (nonzero == 0) ? 1 : 0;
}

__device__ __forceinline__ int load_idx(const int* __restrict__ ei, int pos, int f) {
    return f ? ei[2 * pos] : ei[pos];
}

// ---------------- f16 hi/lo split ----------------
__device__ __forceinline__ void hsplit(float a, _Float16& hi, _Float16& lo) {
    _Float16 h = (_Float16)a;           // RNE
    hi = h;
    lo = (_Float16)(a - (float)h);
}

// ---------------- fused prep: cvt_x | edge->ELL | pack_w ----------------
// pack layout: frag index = ((ks*8 + cf)*64 + lane)*8;
// lane holds B[ks*32 + (lane>>4)*8 + i][cf*16 + (lane&15)]
__global__ void prep_kernel(const float* __restrict__ x, _Float16* __restrict__ xh,
                            const int* __restrict__ ei, const int* __restrict__ flag,
                            int* __restrict__ deg, unsigned short* __restrict__ ell,
                            const float* __restrict__ W0, const float* __restrict__ W1,
                            const float* __restrict__ W2, const float* __restrict__ W3,
                            _Float16* __restrict__ pkh, _Float16* __restrict__ pkl) {
    int b = blockIdx.x;
    if (b < CVT_BLKS) {
        int idx = b * 256 + threadIdx.x;
        if (idx < N_NODES * 32) {
            float4 v = ((const float4*)x)[idx];
            h16x4 o;
            o[0] = (_Float16)v.x; o[1] = (_Float16)v.y;
            o[2] = (_Float16)v.z; o[3] = (_Float16)v.w;
            ((h16x4*)xh)[idx] = o;
        }
    } else if (b < CVT_BLKS + EDGE_BLKS) {
        int base = (b - CVT_BLKS) * 1024;
        int f = *flag;
#pragma unroll
        for (int k = 0; k < 4; ++k) {
            int e = base + k * 256 + threadIdx.x;
            if (e < N_EDGES) {
                int s = load_idx(ei, e, f);
                int d = load_idx(ei, N_EDGES + e, f);
                int pos = atomicAdd(&deg[d], 1);
                if (pos < ELLW) ell[(size_t)d * ELLW + pos] = (unsigned short)s;
            }
        }
    } else {
        int pb = b - CVT_BLKS - EDGE_BLKS;   // 0..31
        int wsel = pb >> 3;
        const float* W = (wsel == 0) ? W0 : (wsel == 1) ? W1 : (wsel == 2) ? W2 : W3;
        int idx = (pb & 7) * 256 + threadIdx.x; // 0..2047
        int lane = idx & 63;
        int cf = (idx >> 6) & 7;
        int ks = idx >> 9;
        int col = cf * 16 + (lane & 15);
        int k0 = ks * 32 + (lane >> 4) * 8;
        _Float16 h[8], l[8];
#pragma unroll
        for (int i = 0; i < 8; ++i) hsplit(W[(size_t)(k0 + i) * HDIM + col], h[i], l[i]);
        size_t base = (size_t)wsel * 16384 + (size_t)idx * 8;
#pragma unroll
        for (int i = 0; i < 8; ++i) { pkh[base + i] = h[i]; pkl[base + i] = l[i]; }
    }
}

// ---------------- dinv from deg ----------------
__global__ void dinv_kernel(const int* __restrict__ deg, float* __restrict__ dinv) {
    int i = blockIdx.x * 256 + threadIdx.x;
    if (i < N_NODES) dinv[i] = rsqrtf((float)deg[i] + 1.0f); // +1 self-loop
}

// ---------------- aggregation from ELL: 4 nodes/wave (16 lanes x 16B), 4-deep ----------------
__global__ __launch_bounds__(256) void agg_kernel(const _Float16* __restrict__ h,
                                                  const float* __restrict__ dinv,
                                                  const int* __restrict__ deg,
                                                  const unsigned short* __restrict__ ell,
                                                  _Float16* __restrict__ out) {
    int node = blockIdx.x * 16 + (threadIdx.x >> 4);
    int sub = threadIdx.x & 15;
    if (node >= N_NODES) return;
    const h16x8* h8 = (const h16x8*)h;
    float dd = dinv[node];
    h16x8 v = h8[(size_t)node * 16 + sub];
    float acc[8];
#pragma unroll
    for (int i = 0; i < 8; ++i) acc[i] = dd * (float)v[i]; // self (×dd below)
    int cnt = min(deg[node], ELLW);
    const unsigned short* row = ell + (size_t)node * ELLW;
    for (int j = 0; j < cnt; j += 4) {
        uint2 pk = *(const uint2*)(row + j);   // 4 ushort (row is 128B-aligned, j%4==0)
        int s0 = (int)(pk.x & 0xFFFFu);
        int s1 = (int)(pk.x >> 16);
        int s2 = (int)(pk.y & 0xFFFFu);
        int s3 = (int)(pk.y >> 16);
        bool k1 = j + 1 < cnt, k2 = j + 2 < cnt, k3 = j + 3 < cnt;
        s1 = k1 ? s1 : s0;                     // clamp: garbage entries may index OOB
        s2 = k2 ? s2 : s0;
        s3 = k3 ? s3 : s0;
        float w0 = dinv[s0];                   // parallel with gather (both depend on s only)
        float w1 = k1 ? dinv[s1] : 0.f;
        float w2 = k2 ? dinv[s2] : 0.f;
        float w3 = k3 ? dinv[s3] : 0.f;
        h16x8 u0 = h8[(size_t)s0 * 16 + sub];
        h16x8 u1 = h8[(size_t)s1 * 16 + sub];
        h16x8 u2 = h8[(size_t)s2 * 16 + sub];
        h16x8 u3 = h8[(size_t)s3 * 16 + sub];
#pragma unroll
        for (int i = 0; i < 8; ++i) {
            acc[i] += w0 * (float)u0[i];
            acc[i] += w1 * (float)u1[i];
            acc[i] += w2 * (float)u2[i];
            acc[i] += w3 * (float)u3[i];
        }
    }
    h16x8 r;
#pragma unroll
    for (int i = 0; i < 8; ++i) r[i] = (_Float16)(acc[i] * dd);
    ((h16x8*)out)[(size_t)node * 16 + sub] = r;
}

// ---------------- MFMA GEMM: f16 A (exact), W split f16 hi/lo -> 2 MFMA/frag ----------------
// mode 0: bias + two-pass LN (*gamma+beta) + ReLU -> fp16 out[row][col]
// mode 1: bias + ReLU, dot w2 (gamma slot) + b2 (beta slot) -> fp32 logits out[row]
__global__ __launch_bounds__(256) void gemm_mfma(const _Float16* __restrict__ A,
                                                 const _Float16* __restrict__ Bh,
                                                 const _Float16* __restrict__ Bl,
                                                 const float* __restrict__ bias,
                                                 const float* __restrict__ gamma,
                                                 const float* __restrict__ beta,
                                                 void* __restrict__ outraw,
                                                 int mode, int nrows) {
    int t = threadIdx.x;
    int wave = t >> 6, lane = t & 63;
    int lrow = lane & 15, lk = lane >> 4;
    int rowb = blockIdx.x * 64 + wave * 16;

    f32x4 acc[8];
#pragma unroll
    for (int cf = 0; cf < 8; ++cf) acc[cf] = (f32x4){0.f, 0.f, 0.f, 0.f};

    const _Float16* arow = A + (size_t)(rowb + lrow) * HDIM;

#pragma unroll
    for (int ks = 0; ks < 4; ++ks) {
        h16x8 a = *(const h16x8*)(arow + ks * 32 + lk * 8); // exact f16 A fragment
        const _Float16* bhp = Bh + (size_t)(ks * 8) * 512 + (size_t)lane * 8;
        const _Float16* blp = Bl + (size_t)(ks * 8) * 512 + (size_t)lane * 8;
#pragma unroll
        for (int cf = 0; cf < 8; ++cf) {
            h16x8 bh = *(const h16x8*)(bhp + (size_t)cf * 512);
            h16x8 bl = *(const h16x8*)(blp + (size_t)cf * 512);
            acc[cf] = __builtin_amdgcn_mfma_f32_16x16x32_f16(a, bh, acc[cf], 0, 0, 0);
            acc[cf] = __builtin_amdgcn_mfma_f32_16x16x32_f16(a, bl, acc[cf], 0, 0, 0);
        }
    }

    // C/D layout: col = cf*16 + lrow, local row = lk*4 + r
    float bias_v[8];
#pragma unroll
    for (int cf = 0; cf < 8; ++cf) bias_v[cf] = bias[cf * 16 + lrow];

    if (mode == 0) {
        _Float16* out = (_Float16*)outraw;
        float gam[8], bet[8];
#pragma unroll
        for (int cf = 0; cf < 8; ++cf) {
            gam[cf] = gamma[cf * 16 + lrow];
            bet[cf] = beta[cf * 16 + lrow];
        }
#pragma unroll
        for (int r = 0; r < 4; ++r) {
            float vv[8];
            float s1 = 0.f;
#pragma unroll
            for (int cf = 0; cf < 8; ++cf) {
                vv[cf] = acc[cf][r] + bias_v[cf];
                s1 += vv[cf];
            }
#pragma unroll
            for (int m = 1; m <= 8; m <<= 1) s1 += __shfl_xor(s1, m);
            float mean = s1 * (1.0f / 128.0f);
            float s2 = 0.f;
            float cc[8];
#pragma unroll
            for (int cf = 0; cf < 8; ++cf) {
                cc[cf] = vv[cf] - mean;
                s2 += cc[cf] * cc[cf];
            }
#pragma unroll
            for (int m = 1; m <= 8; m <<= 1) s2 += __shfl_xor(s2, m);
            float var = s2 * (1.0f / 128.0f);
            float rs = rsqrtf(var + EPS);
            int row = rowb + lk * 4 + r;
            if (row < nrows) {
#pragma unroll
                for (int cf = 0; cf < 8; ++cf) {
                    float y = cc[cf] * rs * gam[cf] + bet[cf];
                    out[(size_t)row * HDIM + cf * 16 + lrow] = (_Float16)(y > 0.f ? y : 0.f);
                }
            }
        }
    } else {
        float* out = (float*)outraw;
        float w2v[8];
#pragma unroll
        for (int cf = 0; cf < 8; ++cf) w2v[cf] = gamma[cf * 16 + lrow];
        float b2 = beta[0];
#pragma unroll
        for (int r = 0; r < 4; ++r) {
            float part = 0.f;
#pragma unroll
            for (int cf = 0; cf < 8; ++cf) {
                float y = acc[cf][r] + bias_v[cf];
                y = y > 0.f ? y : 0.f;
                part += y * w2v[cf];
            }
#pragma unroll
            for (int m = 1; m <= 8; m <<= 1) part += __shfl_xor(part, m);
            int row = rowb + lk * 4 + r;
            if (row < nrows && lrow == 0) out[row] = part + b2;
        }
    }
}

extern "C" void kernel_launch(void* const* d_in, const int* in_sizes, int n_in,
                              void* d_out, int out_size, void* d_ws, size_t ws_size,
                              hipStream_t stream) {
    (void)in_sizes; (void)n_in; (void)out_size; (void)ws_size;
    const float* x   = (const float*)d_in[0];
    const int*   ei  = (const int*)d_in[1];
    const float* W0  = (const float*)d_in[2];
    const float* b0  = (const float*)d_in[3];
    const float* g0  = (const float*)d_in[4];
    const float* be0 = (const float*)d_in[5];
    const float* W1  = (const float*)d_in[6];
    const float* b1  = (const float*)d_in[7];
    const float* g1  = (const float*)d_in[8];
    const float* be1 = (const float*)d_in[9];
    const float* W2  = (const float*)d_in[10];
    const float* b2  = (const float*)d_in[11];
    const float* g2  = (const float*)d_in[12];
    const float* be2 = (const float*)d_in[13];
    const float* hW1 = (const float*)d_in[14];
    const float* hb1 = (const float*)d_in[15];
    const float* hW2 = (const float*)d_in[16];
    const float* hb2 = (const float*)d_in[17];
    float* out = (float*)d_out;

    char* w = (char*)d_ws;
    size_t off = 0;
    auto alloc = [&](size_t bytes) -> void* {
        void* p = w + off;
        off += (bytes + 255) & ~(size_t)255;
        return p;
    };
    float*          dinv = (float*)alloc((size_t)N_NODES * 4);
    int*            deg  = (int*)alloc((size_t)N_NODES * 4);
    unsigned short* ell  = (unsigned short*)alloc((size_t)N_NODES * ELLW * 2);
    int*            flag = (int*)alloc(256);
    _Float16*       hagg = (_Float16*)alloc((size_t)N_NODES * HDIM * 2);
    _Float16*       xh   = (_Float16*)alloc((size_t)N_NODES * HDIM * 2);
    _Float16*       hA   = (_Float16*)alloc((size_t)N_NODES * HDIM * 2);
    _Float16*       hB   = (_Float16*)alloc((size_t)N_NODES * HDIM * 2);
    _Float16*       pkh  = (_Float16*)alloc((size_t)4 * 16384 * 2);
    _Float16*       pkl  = (_Float16*)alloc((size_t)4 * 16384 * 2);

    hipMemsetAsync(deg, 0, (size_t)N_NODES * 4, stream);

    detect_kernel<<<1, 256, 0, stream>>>(ei, flag);
    prep_kernel<<<CVT_BLKS + EDGE_BLKS + PACK_BLKS, 256, 0, stream>>>(
        x, xh, ei, flag, deg, ell, W0, W1, W2, hW1, pkh, pkl);
    dinv_kernel<<<(N_NODES + 255) / 256, 256, 0, stream>>>(deg, dinv);

    int nab = (N_NODES + 15) / 16; // 3125
    int ngb = (N_NODES + 63) / 64; // 782
    // layer 0: xh -> hagg -> hA
    agg_kernel<<<nab, 256, 0, stream>>>(xh, dinv, deg, ell, hagg);
    gemm_mfma<<<ngb, 256, 0, stream>>>(hagg, pkh, pkl, b0, g0, be0, hA, 0, N_NODES);
    // layer 1: hA -> hagg -> hB
    agg_kernel<<<nab, 256, 0, stream>>>(hA, dinv, deg, ell, hagg);
    gemm_mfma<<<ngb, 256, 0, stream>>>(hagg, pkh + (size_t)16384, pkl + (size_t)16384,
                                       b1, g1, be1, hB, 0, N_NODES);
    // layer 2: hB -> hagg -> hA
    agg_kernel<<<nab, 256, 0, stream>>>(hB, dinv, deg, ell, hagg);
    gemm_mfma<<<ngb, 256, 0, stream>>>(hagg, pkh + (size_t)2 * 16384, pkl + (size_t)2 * 16384,
                                       b2, g2, be2, hA, 0, N_NODES);
    // fused head: ReLU(hA @ hW1 + hb1) @ hW2 + hb2 -> logits
    gemm_mfma<<<ngb, 256, 0, stream>>>(hA, pkh + (size_t)3 * 16384, pkl + (size_t)3 * 16384,
                                       hb1, hW2, hb2, out, 1, N_NODES);
}

// Round 11
// 184.464 us; speedup vs baseline: 1.5797x; 1.0220x over previous
//
#include <hip/hip_runtime.h>
#include <hip/hip_fp16.h>

#define N_NODES 50000
#define N_EDGES 600000
#define HDIM 128
#define EPS 1e-5f
#define ELLW 64

typedef __attribute__((ext_vector_type(4))) float f32x4;
typedef __attribute__((ext_vector_type(4))) _Float16 h16x4;
typedef __attribute__((ext_vector_type(8))) _Float16 h16x8;

#define EDGE_BLKS ((N_EDGES + 255) / 256)    // 1 edge per thread, FIRST in grid
#define CVT_BLKS 6250                        // N_NODES*32 float4 / 256
#define PACK_BLKS 32                         // 4 weights x 8 blocks

// ---------------- edge_index dtype detection (int32 vs int64) ----------------
__global__ void detect_kernel(const int* __restrict__ ei, int* __restrict__ flag) {
    __shared__ int nonzero;
    if (threadIdx.x == 0) nonzero = 0;
    __syncthreads();
    int acc = 0;
    for (int i = threadIdx.x; i < 1024; i += blockDim.x)
        acc |= ei[2 * i + 1];
    if (acc) atomicOr(&nonzero, 1);
    __syncthreads();
    if (threadIdx.x == 0) *flag = (nonzero == 0) ? 1 : 0;
}

__device__ __forceinline__ int load_idx(const int* __restrict__ ei, int pos, int f) {
    return f ? ei[2 * pos] : ei[pos];
}

// ---------------- f16 hi/lo split ----------------
__device__ __forceinline__ void hsplit(float a, _Float16& hi, _Float16& lo) {
    _Float16 h = (_Float16)a;           // RNE
    hi = h;
    lo = (_Float16)(a - (float)h);
}

// ---------------- fused prep: edge->ELL (first!) | cvt_x | pack_w ----------------
// pack layout: frag index = ((ks*8 + cf)*64 + lane)*8;
// lane holds B[ks*32 + (lane>>4)*8 + i][cf*16 + (lane&15)]
__global__ void prep_kernel(const float* __restrict__ x, _Float16* __restrict__ xh,
                            const int* __restrict__ ei, const int* __restrict__ flag,
                            int* __restrict__ deg, unsigned short* __restrict__ ell,
                            const float* __restrict__ W0, const float* __restrict__ W1,
                            const float* __restrict__ W2, const float* __restrict__ W3,
                            _Float16* __restrict__ pkh, _Float16* __restrict__ pkl) {
    int b = blockIdx.x;
    if (b < EDGE_BLKS) {
        // edge phase first: minimal competing L2 traffic while ell/deg lines are hot
        int e = b * 256 + threadIdx.x;
        if (e < N_EDGES) {
            int f = *flag;
            int s = load_idx(ei, e, f);
            int d = load_idx(ei, N_EDGES + e, f);
            int pos = atomicAdd(&deg[d], 1);
            if (pos < ELLW) ell[(size_t)d * ELLW + pos] = (unsigned short)s;
        }
    } else if (b < EDGE_BLKS + CVT_BLKS) {
        int idx = (b - EDGE_BLKS) * 256 + threadIdx.x;
        if (idx < N_NODES * 32) {
            float4 v = ((const float4*)x)[idx];
            h16x4 o;
            o[0] = (_Float16)v.x; o[1] = (_Float16)v.y;
            o[2] = (_Float16)v.z; o[3] = (_Float16)v.w;
            ((h16x4*)xh)[idx] = o;
        }
    } else {
        int pb = b - EDGE_BLKS - CVT_BLKS;   // 0..31
        int wsel = pb >> 3;
        const float* W = (wsel == 0) ? W0 : (wsel == 1) ? W1 : (wsel == 2) ? W2 : W3;
        int idx = (pb & 7) * 256 + threadIdx.x; // 0..2047
        int lane = idx & 63;
        int cf = (idx >> 6) & 7;
        int ks = idx >> 9;
        int col = cf * 16 + (lane & 15);
        int k0 = ks * 32 + (lane >> 4) * 8;
        _Float16 h[8], l[8];
#pragma unroll
        for (int i = 0; i < 8; ++i) hsplit(W[(size_t)(k0 + i) * HDIM + col], h[i], l[i]);
        size_t base = (size_t)wsel * 16384 + (size_t)idx * 8;
#pragma unroll
        for (int i = 0; i < 8; ++i) { pkh[base + i] = h[i]; pkl[base + i] = l[i]; }
    }
}

// ---------------- aggregation from ELL: 4 nodes/wave (16 lanes x 16B), 4-deep ----------------
// dinv computed inline: rsqrtf(deg+1)  (VALU is idle; saves the dinv kernel+launch)
__global__ __launch_bounds__(256) void agg_kernel(const _Float16* __restrict__ h,
                                                  const int* __restrict__ deg,
                                                  const unsigned short* __restrict__ ell,
                                                  _Float16* __restrict__ out) {
    int node = blockIdx.x * 16 + (threadIdx.x >> 4);
    int sub = threadIdx.x & 15;
    if (node >= N_NODES) return;
    const h16x8* h8 = (const h16x8*)h;
    int dn = deg[node];
    float dd = rsqrtf((float)dn + 1.0f);
    h16x8 v = h8[(size_t)node * 16 + sub];
    float acc[8];
#pragma unroll
    for (int i = 0; i < 8; ++i) acc[i] = dd * (float)v[i]; // self (×dd below)
    int cnt = min(dn, ELLW);
    const unsigned short* row = ell + (size_t)node * ELLW;
    for (int j = 0; j < cnt; j += 4) {
        uint2 pk = *(const uint2*)(row + j);   // 4 ushort (row 128B-aligned, j%4==0)
        int s0 = (int)(pk.x & 0xFFFFu);
        int s1 = (int)(pk.x >> 16);
        int s2 = (int)(pk.y & 0xFFFFu);
        int s3 = (int)(pk.y >> 16);
        bool k1 = j + 1 < cnt, k2 = j + 2 < cnt, k3 = j + 3 < cnt;
        s1 = k1 ? s1 : s0;                     // clamp garbage to a safe row
        s2 = k2 ? s2 : s0;
        s3 = k3 ? s3 : s0;
        int d0 = deg[s0];                      // parallel with h-gather (dep on s only)
        int d1 = deg[s1];
        int d2 = deg[s2];
        int d3 = deg[s3];
        h16x8 u0 = h8[(size_t)s0 * 16 + sub];
        h16x8 u1 = h8[(size_t)s1 * 16 + sub];
        h16x8 u2 = h8[(size_t)s2 * 16 + sub];
        h16x8 u3 = h8[(size_t)s3 * 16 + sub];
        float w0 = rsqrtf((float)d0 + 1.0f);
        float w1 = k1 ? rsqrtf((float)d1 + 1.0f) : 0.f;
        float w2 = k2 ? rsqrtf((float)d2 + 1.0f) : 0.f;
        float w3 = k3 ? rsqrtf((float)d3 + 1.0f) : 0.f;
#pragma unroll
        for (int i = 0; i < 8; ++i) {
            acc[i] += w0 * (float)u0[i];
            acc[i] += w1 * (float)u1[i];
            acc[i] += w2 * (float)u2[i];
            acc[i] += w3 * (float)u3[i];
        }
    }
    h16x8 r;
#pragma unroll
    for (int i = 0; i < 8; ++i) r[i] = (_Float16)(acc[i] * dd);
    ((h16x8*)out)[(size_t)node * 16 + sub] = r;
}

// ---------------- MFMA GEMM: f16 A (exact), W split f16 hi/lo -> 2 MFMA/frag ----------------
// mode 0: bias + two-pass LN (*gamma+beta) + ReLU -> fp16 out[row][col]
// mode 1: bias + ReLU, dot w2 (gamma slot) + b2 (beta slot) -> fp32 logits out[row]
__global__ __launch_bounds__(256) void gemm_mfma(const _Float16* __restrict__ A,
                                                 const _Float16* __restrict__ Bh,
                                                 const _Float16* __restrict__ Bl,
                                                 const float* __restrict__ bias,
                                                 const float* __restrict__ gamma,
                                                 const float* __restrict__ beta,
                                                 void* __restrict__ outraw,
                                                 int mode, int nrows) {
    int t = threadIdx.x;
    int wave = t >> 6, lane = t & 63;
    int lrow = lane & 15, lk = lane >> 4;
    int rowb = blockIdx.x * 64 + wave * 16;

    f32x4 acc[8];
#pragma unroll
    for (int cf = 0; cf < 8; ++cf) acc[cf] = (f32x4){0.f, 0.f, 0.f, 0.f};

    const _Float16* arow = A + (size_t)(rowb + lrow) * HDIM;

#pragma unroll
    for (int ks = 0; ks < 4; ++ks) {
        h16x8 a = *(const h16x8*)(arow + ks * 32 + lk * 8); // exact f16 A fragment
        const _Float16* bhp = Bh + (size_t)(ks * 8) * 512 + (size_t)lane * 8;
        const _Float16* blp = Bl + (size_t)(ks * 8) * 512 + (size_t)lane * 8;
#pragma unroll
        for (int cf = 0; cf < 8; ++cf) {
            h16x8 bh = *(const h16x8*)(bhp + (size_t)cf * 512);
            h16x8 bl = *(const h16x8*)(blp + (size_t)cf * 512);
            acc[cf] = __builtin_amdgcn_mfma_f32_16x16x32_f16(a, bh, acc[cf], 0, 0, 0);
            acc[cf] = __builtin_amdgcn_mfma_f32_16x16x32_f16(a, bl, acc[cf], 0, 0, 0);
        }
    }

    // C/D layout: col = cf*16 + lrow, local row = lk*4 + r
    float bias_v[8];
#pragma unroll
    for (int cf = 0; cf < 8; ++cf) bias_v[cf] = bias[cf * 16 + lrow];

    if (mode == 0) {
        _Float16* out = (_Float16*)outraw;
        float gam[8], bet[8];
#pragma unroll
        for (int cf = 0; cf < 8; ++cf) {
            gam[cf] = gamma[cf * 16 + lrow];
            bet[cf] = beta[cf * 16 + lrow];
        }
#pragma unroll
        for (int r = 0; r < 4; ++r) {
            float vv[8];
            float s1 = 0.f;
#pragma unroll
            for (int cf = 0; cf < 8; ++cf) {
                vv[cf] = acc[cf][r] + bias_v[cf];
                s1 += vv[cf];
            }
#pragma unroll
            for (int m = 1; m <= 8; m <<= 1) s1 += __shfl_xor(s1, m);
            float mean = s1 * (1.0f / 128.0f);
            float s2 = 0.f;
            float cc[8];
#pragma unroll
            for (int cf = 0; cf < 8; ++cf) {
                cc[cf] = vv[cf] - mean;
                s2 += cc[cf] * cc[cf];
            }
#pragma unroll
            for (int m = 1; m <= 8; m <<= 1) s2 += __shfl_xor(s2, m);
            float var = s2 * (1.0f / 128.0f);
            float rs = rsqrtf(var + EPS);
            int row = rowb + lk * 4 + r;
            if (row < nrows) {
#pragma unroll
                for (int cf = 0; cf < 8; ++cf) {
                    float y = cc[cf] * rs * gam[cf] + bet[cf];
                    out[(size_t)row * HDIM + cf * 16 + lrow] = (_Float16)(y > 0.f ? y : 0.f);
                }
            }
        }
    } else {
        float* out = (float*)outraw;
        float w2v[8];
#pragma unroll
        for (int cf = 0; cf < 8; ++cf) w2v[cf] = gamma[cf * 16 + lrow];
        float b2 = beta[0];
#pragma unroll
        for (int r = 0; r < 4; ++r) {
            float part = 0.f;
#pragma unroll
            for (int cf = 0; cf < 8; ++cf) {
                float y = acc[cf][r] + bias_v[cf];
                y = y > 0.f ? y : 0.f;
                part += y * w2v[cf];
            }
#pragma unroll
            for (int m = 1; m <= 8; m <<= 1) part += __shfl_xor(part, m);
            int row = rowb + lk * 4 + r;
            if (row < nrows && lrow == 0) out[row] = part + b2;
        }
    }
}

extern "C" void kernel_launch(void* const* d_in, const int* in_sizes, int n_in,
                              void* d_out, int out_size, void* d_ws, size_t ws_size,
                              hipStream_t stream) {
    (void)in_sizes; (void)n_in; (void)out_size; (void)ws_size;
    const float* x   = (const float*)d_in[0];
    const int*   ei  = (const int*)d_in[1];
    const float* W0  = (const float*)d_in[2];
    const float* b0  = (const float*)d_in[3];
    const float* g0  = (const float*)d_in[4];
    const float* be0 = (const float*)d_in[5];
    const float* W1  = (const float*)d_in[6];
    const float* b1  = (const float*)d_in[7];
    const float* g1  = (const float*)d_in[8];
    const float* be1 = (const float*)d_in[9];
    const float* W2  = (const float*)d_in[10];
    const float* b2  = (const float*)d_in[11];
    const float* g2  = (const float*)d_in[12];
    const float* be2 = (const float*)d_in[13];
    const float* hW1 = (const float*)d_in[14];
    const float* hb1 = (const float*)d_in[15];
    const float* hW2 = (const float*)d_in[16];
    const float* hb2 = (const float*)d_in[17];
    float* out = (float*)d_out;

    char* w = (char*)d_ws;
    size_t off = 0;
    auto alloc = [&](size_t bytes) -> void* {
        void* p = w + off;
        off += (bytes + 255) & ~(size_t)255;
        return p;
    };
    int*            deg  = (int*)alloc((size_t)N_NODES * 4);
    unsigned short* ell  = (unsigned short*)alloc((size_t)N_NODES * ELLW * 2);
    int*            flag = (int*)alloc(256);
    _Float16*       hagg = (_Float16*)alloc((size_t)N_NODES * HDIM * 2);
    _Float16*       xh   = (_Float16*)alloc((size_t)N_NODES * HDIM * 2);
    _Float16*       hA   = (_Float16*)alloc((size_t)N_NODES * HDIM * 2);
    _Float16*       hB   = (_Float16*)alloc((size_t)N_NODES * HDIM * 2);
    _Float16*       pkh  = (_Float16*)alloc((size_t)4 * 16384 * 2);
    _Float16*       pkl  = (_Float16*)alloc((size_t)4 * 16384 * 2);

    hipMemsetAsync(deg, 0, (size_t)N_NODES * 4, stream);

    detect_kernel<<<1, 256, 0, stream>>>(ei, flag);
    prep_kernel<<<EDGE_BLKS + CVT_BLKS + PACK_BLKS, 256, 0, stream>>>(
        x, xh, ei, flag, deg, ell, W0, W1, W2, hW1, pkh, pkl);

    int nab = (N_NODES + 15) / 16; // 3125
    int ngb = (N_NODES + 63) / 64; // 782
    // layer 0: xh -> hagg -> hA
    agg_kernel<<<nab, 256, 0, stream>>>(xh, deg, ell, hagg);
    gemm_mfma<<<ngb, 256, 0, stream>>>(hagg, pkh, pkl, b0, g0, be0, hA, 0, N_NODES);
    // layer 1: hA -> hagg -> hB
    agg_kernel<<<nab, 256, 0, stream>>>(hA, deg, ell, hagg);
    gemm_mfma<<<ngb, 256, 0, stream>>>(hagg, pkh + (size_t)16384, pkl + (size_t)16384,
                                       b1, g1, be1, hB, 0, N_NODES);
    // layer 2: hB -> hagg -> hA
    agg_kernel<<<nab, 256, 0, stream>>>(hB, deg, ell, hagg);
    gemm_mfma<<<ngb, 256, 0, stream>>>(hagg, pkh + (size_t)2 * 16384, pkl + (size_t)2 * 16384,
                                       b2, g2, be2, hA, 0, N_NODES);
    // fused head: ReLU(hA @ hW1 + hb1) @ hW2 + hb2 -> logits
    gemm_mfma<<<ngb, 256, 0, stream>>>(hA, pkh + (size_t)3 * 16384, pkl + (size_t)3 * 16384,
                                       hb1, hW2, hb2, out, 1, N_NODES);
}

// Round 12
// 172.197 us; speedup vs baseline: 1.6922x; 1.0712x over previous
//
#include <hip/hip_runtime.h>
#include <hip/hip_fp16.h>

#define N_NODES 50000
#define N_EDGES 600000
#define HDIM 128
#define EPS 1e-5f
#define ELLW 64
#define LPADH 136   // fp16 pad: row stride 272B = 17x16B (aligned b128, 8-bank spread)

typedef __attribute__((ext_vector_type(4))) float f32x4;
typedef __attribute__((ext_vector_type(4))) _Float16 h16x4;
typedef __attribute__((ext_vector_type(8))) _Float16 h16x8;

#define EDGE_BLKS ((N_EDGES + 255) / 256)    // 1 edge per thread, FIRST in grid
#define CVT_BLKS 6250                        // N_NODES*32 float4 / 256
#define PACK_BLKS 32                         // 4 weights x 8 blocks

// ---------------- edge_index dtype detection (int32 vs int64) ----------------
__global__ void detect_kernel(const int* __restrict__ ei, int* __restrict__ flag) {
    __shared__ int nonzero;
    if (threadIdx.x == 0) nonzero = 0;
    __syncthreads();
    int acc = 0;
    for (int i = threadIdx.x; i < 1024; i += blockDim.x)
        acc |= ei[2 * i + 1];
    if (acc) atomicOr(&nonzero, 1);
    __syncthreads();
    if (threadIdx.x == 0) *flag = (nonzero == 0) ? 1 : 0;
}

__device__ __forceinline__ int load_idx(const int* __restrict__ ei, int pos, int f) {
    return f ? ei[2 * pos] : ei[pos];
}

// ---------------- f16 hi/lo split ----------------
__device__ __forceinline__ void hsplit(float a, _Float16& hi, _Float16& lo) {
    _Float16 h = (_Float16)a;           // RNE
    hi = h;
    lo = (_Float16)(a - (float)h);
}

// ---------------- fused prep: edge->ELL (first) | cvt_x | pack_w ----------------
__global__ void prep_kernel(const float* __restrict__ x, _Float16* __restrict__ xh,
                            const int* __restrict__ ei, const int* __restrict__ flag,
                            int* __restrict__ deg, unsigned short* __restrict__ ell,
                            const float* __restrict__ W0, const float* __restrict__ W1,
                            const float* __restrict__ W2, const float* __restrict__ W3,
                            _Float16* __restrict__ pkh, _Float16* __restrict__ pkl) {
    int b = blockIdx.x;
    if (b < EDGE_BLKS) {
        int e = b * 256 + threadIdx.x;
        if (e < N_EDGES) {
            int f = *flag;
            int s = load_idx(ei, e, f);
            int d = load_idx(ei, N_EDGES + e, f);
            int pos = atomicAdd(&deg[d], 1);
            if (pos < ELLW) ell[(size_t)d * ELLW + pos] = (unsigned short)s;
        }
    } else if (b < EDGE_BLKS + CVT_BLKS) {
        int idx = (b - EDGE_BLKS) * 256 + threadIdx.x;
        if (idx < N_NODES * 32) {
            float4 v = ((const float4*)x)[idx];
            h16x4 o;
            o[0] = (_Float16)v.x; o[1] = (_Float16)v.y;
            o[2] = (_Float16)v.z; o[3] = (_Float16)v.w;
            ((h16x4*)xh)[idx] = o;
        }
    } else {
        int pb = b - EDGE_BLKS - CVT_BLKS;   // 0..31
        int wsel = pb >> 3;
        const float* W = (wsel == 0) ? W0 : (wsel == 1) ? W1 : (wsel == 2) ? W2 : W3;
        int idx = (pb & 7) * 256 + threadIdx.x; // 0..2047
        int lane = idx & 63;
        int cf = (idx >> 6) & 7;
        int ks = idx >> 9;
        int col = cf * 16 + (lane & 15);
        int k0 = ks * 32 + (lane >> 4) * 8;
        _Float16 h[8], l[8];
#pragma unroll
        for (int i = 0; i < 8; ++i) hsplit(W[(size_t)(k0 + i) * HDIM + col], h[i], l[i]);
        size_t base = (size_t)wsel * 16384 + (size_t)idx * 8;
#pragma unroll
        for (int i = 0; i < 8; ++i) { pkh[base + i] = h[i]; pkl[base + i] = l[i]; }
    }
}

// ---------------- fused layer: ELL-aggregate 64 rows -> LDS(fp16) -> MFMA -> LN -> ReLU ----------------
__global__ __launch_bounds__(256) void layer_fused(const _Float16* __restrict__ h,
                                                   const int* __restrict__ deg,
                                                   const unsigned short* __restrict__ ell,
                                                   const _Float16* __restrict__ Bh,
                                                   const _Float16* __restrict__ Bl,
                                                   const float* __restrict__ bias,
                                                   const float* __restrict__ gamma,
                                                   const float* __restrict__ beta,
                                                   _Float16* __restrict__ out, int nrows) {
    __shared__ _Float16 As[64][LPADH]; // 17.4 KB
    int t = threadIdx.x;
    int blockRow = blockIdx.x * 64;

    // ---- phase 1: gather/aggregate (16 groups of 16 lanes; 4 nodes each) ----
    {
        int g = t >> 4, sub = t & 15;
        const h16x8* h8 = (const h16x8*)h;
        for (int j = 0; j < 4; ++j) {
            int rl = j * 16 + g;
            int node = blockRow + rl;
            h16x8 r;
            if (node < nrows) {
                int dn = deg[node];
                float dd = rsqrtf((float)dn + 1.0f);
                h16x8 v = h8[(size_t)node * 16 + sub];
                float acc[8];
#pragma unroll
                for (int i = 0; i < 8; ++i) acc[i] = dd * (float)v[i];
                int cnt = min(dn, ELLW);
                const unsigned short* row = ell + (size_t)node * ELLW;
                for (int e = 0; e < cnt; e += 4) {
                    uint2 pk = *(const uint2*)(row + e);
                    int s0 = (int)(pk.x & 0xFFFFu);
                    int s1 = (int)(pk.x >> 16);
                    int s2 = (int)(pk.y & 0xFFFFu);
                    int s3 = (int)(pk.y >> 16);
                    bool k1 = e + 1 < cnt, k2 = e + 2 < cnt, k3 = e + 3 < cnt;
                    s1 = k1 ? s1 : s0;
                    s2 = k2 ? s2 : s0;
                    s3 = k3 ? s3 : s0;
                    int d0 = deg[s0];
                    int d1 = deg[s1];
                    int d2 = deg[s2];
                    int d3 = deg[s3];
                    h16x8 u0 = h8[(size_t)s0 * 16 + sub];
                    h16x8 u1 = h8[(size_t)s1 * 16 + sub];
                    h16x8 u2 = h8[(size_t)s2 * 16 + sub];
                    h16x8 u3 = h8[(size_t)s3 * 16 + sub];
                    float w0 = rsqrtf((float)d0 + 1.0f);
                    float w1 = k1 ? rsqrtf((float)d1 + 1.0f) : 0.f;
                    float w2 = k2 ? rsqrtf((float)d2 + 1.0f) : 0.f;
                    float w3 = k3 ? rsqrtf((float)d3 + 1.0f) : 0.f;
#pragma unroll
                    for (int i = 0; i < 8; ++i) {
                        acc[i] += w0 * (float)u0[i];
                        acc[i] += w1 * (float)u1[i];
                        acc[i] += w2 * (float)u2[i];
                        acc[i] += w3 * (float)u3[i];
                    }
                }
#pragma unroll
                for (int i = 0; i < 8; ++i) r[i] = (_Float16)(acc[i] * dd);
            } else {
#pragma unroll
                for (int i = 0; i < 8; ++i) r[i] = (_Float16)0.f;
            }
            *(h16x8*)&As[rl][sub * 8] = r;
        }
    }
    __syncthreads();

    // ---- phase 2: MFMA (f16 A exact, W hi/lo) + bias + two-pass LN + ReLU ----
    int wave = t >> 6, lane = t & 63;
    int lrow = lane & 15, lk = lane >> 4;
    int rowb = blockRow + wave * 16;

    f32x4 acc[8];
#pragma unroll
    for (int cf = 0; cf < 8; ++cf) acc[cf] = (f32x4){0.f, 0.f, 0.f, 0.f};

#pragma unroll
    for (int ks = 0; ks < 4; ++ks) {
        h16x8 a = *(const h16x8*)&As[wave * 16 + lrow][ks * 32 + lk * 8];
        const _Float16* bhp = Bh + (size_t)(ks * 8) * 512 + (size_t)lane * 8;
        const _Float16* blp = Bl + (size_t)(ks * 8) * 512 + (size_t)lane * 8;
#pragma unroll
        for (int cf = 0; cf < 8; ++cf) {
            h16x8 bh = *(const h16x8*)(bhp + (size_t)cf * 512);
            h16x8 bl = *(const h16x8*)(blp + (size_t)cf * 512);
            acc[cf] = __builtin_amdgcn_mfma_f32_16x16x32_f16(a, bh, acc[cf], 0, 0, 0);
            acc[cf] = __builtin_amdgcn_mfma_f32_16x16x32_f16(a, bl, acc[cf], 0, 0, 0);
        }
    }

    float bias_v[8], gam[8], bet[8];
#pragma unroll
    for (int cf = 0; cf < 8; ++cf) {
        bias_v[cf] = bias[cf * 16 + lrow];
        gam[cf] = gamma[cf * 16 + lrow];
        bet[cf] = beta[cf * 16 + lrow];
    }
#pragma unroll
    for (int r = 0; r < 4; ++r) {
        float vv[8];
        float s1 = 0.f;
#pragma unroll
        for (int cf = 0; cf < 8; ++cf) {
            vv[cf] = acc[cf][r] + bias_v[cf];
            s1 += vv[cf];
        }
#pragma unroll
        for (int m = 1; m <= 8; m <<= 1) s1 += __shfl_xor(s1, m);
        float mean = s1 * (1.0f / 128.0f);
        float s2 = 0.f;
        float cc[8];
#pragma unroll
        for (int cf = 0; cf < 8; ++cf) {
            cc[cf] = vv[cf] - mean;
            s2 += cc[cf] * cc[cf];
        }
#pragma unroll
        for (int m = 1; m <= 8; m <<= 1) s2 += __shfl_xor(s2, m);
        float var = s2 * (1.0f / 128.0f);
        float rs = rsqrtf(var + EPS);
        int row = rowb + lk * 4 + r;
        if (row < nrows) {
#pragma unroll
            for (int cf = 0; cf < 8; ++cf) {
                float y = cc[cf] * rs * gam[cf] + bet[cf];
                out[(size_t)row * HDIM + cf * 16 + lrow] = (_Float16)(y > 0.f ? y : 0.f);
            }
        }
    }
}

// ---------------- head: logits = ReLU(A@hW1+hb1)@hW2 + hb2 (A fp16 global) ----------------
__global__ __launch_bounds__(256) void head_mfma(const _Float16* __restrict__ A,
                                                 const _Float16* __restrict__ Bh,
                                                 const _Float16* __restrict__ Bl,
                                                 const float* __restrict__ bias,
                                                 const float* __restrict__ w2,
                                                 const float* __restrict__ b2p,
                                                 float* __restrict__ out, int nrows) {
    int t = threadIdx.x;
    int wave = t >> 6, lane = t & 63;
    int lrow = lane & 15, lk = lane >> 4;
    int rowb = blockIdx.x * 64 + wave * 16;

    f32x4 acc[8];
#pragma unroll
    for (int cf = 0; cf < 8; ++cf) acc[cf] = (f32x4){0.f, 0.f, 0.f, 0.f};

    const _Float16* arow = A + (size_t)(rowb + lrow) * HDIM;
#pragma unroll
    for (int ks = 0; ks < 4; ++ks) {
        h16x8 a = *(const h16x8*)(arow + ks * 32 + lk * 8);
        const _Float16* bhp = Bh + (size_t)(ks * 8) * 512 + (size_t)lane * 8;
        const _Float16* blp = Bl + (size_t)(ks * 8) * 512 + (size_t)lane * 8;
#pragma unroll
        for (int cf = 0; cf < 8; ++cf) {
            h16x8 bh = *(const h16x8*)(bhp + (size_t)cf * 512);
            h16x8 bl = *(const h16x8*)(blp + (size_t)cf * 512);
            acc[cf] = __builtin_amdgcn_mfma_f32_16x16x32_f16(a, bh, acc[cf], 0, 0, 0);
            acc[cf] = __builtin_amdgcn_mfma_f32_16x16x32_f16(a, bl, acc[cf], 0, 0, 0);
        }
    }

    float bias_v[8], w2v[8];
#pragma unroll
    for (int cf = 0; cf < 8; ++cf) {
        bias_v[cf] = bias[cf * 16 + lrow];
        w2v[cf] = w2[cf * 16 + lrow];
    }
    float b2 = b2p[0];
#pragma unroll
    for (int r = 0; r < 4; ++r) {
        float part = 0.f;
#pragma unroll
        for (int cf = 0; cf < 8; ++cf) {
            float y = acc[cf][r] + bias_v[cf];
            y = y > 0.f ? y : 0.f;
            part += y * w2v[cf];
        }
#pragma unroll
        for (int m = 1; m <= 8; m <<= 1) part += __shfl_xor(part, m);
        int row = rowb + lk * 4 + r;
        if (row < nrows && lrow == 0) out[row] = part + b2;
    }
}

extern "C" void kernel_launch(void* const* d_in, const int* in_sizes, int n_in,
                              void* d_out, int out_size, void* d_ws, size_t ws_size,
                              hipStream_t stream) {
    (void)in_sizes; (void)n_in; (void)out_size; (void)ws_size;
    const float* x   = (const float*)d_in[0];
    const int*   ei  = (const int*)d_in[1];
    const float* W0  = (const float*)d_in[2];
    const float* b0  = (const float*)d_in[3];
    const float* g0  = (const float*)d_in[4];
    const float* be0 = (const float*)d_in[5];
    const float* W1  = (const float*)d_in[6];
    const float* b1  = (const float*)d_in[7];
    const float* g1  = (const float*)d_in[8];
    const float* be1 = (const float*)d_in[9];
    const float* W2  = (const float*)d_in[10];
    const float* b2  = (const float*)d_in[11];
    const float* g2  = (const float*)d_in[12];
    const float* be2 = (const float*)d_in[13];
    const float* hW1 = (const float*)d_in[14];
    const float* hb1 = (const float*)d_in[15];
    const float* hW2 = (const float*)d_in[16];
    const float* hb2 = (const float*)d_in[17];
    float* out = (float*)d_out;

    char* w = (char*)d_ws;
    size_t off = 0;
    auto alloc = [&](size_t bytes) -> void* {
        void* p = w + off;
        off += (bytes + 255) & ~(size_t)255;
        return p;
    };
    int*            deg  = (int*)alloc((size_t)N_NODES * 4);
    unsigned short* ell  = (unsigned short*)alloc((size_t)N_NODES * ELLW * 2);
    int*            flag = (int*)alloc(256);
    _Float16*       xh   = (_Float16*)alloc((size_t)N_NODES * HDIM * 2);
    _Float16*       hA   = (_Float16*)alloc((size_t)N_NODES * HDIM * 2);
    _Float16*       hB   = (_Float16*)alloc((size_t)N_NODES * HDIM * 2);
    _Float16*       pkh  = (_Float16*)alloc((size_t)4 * 16384 * 2);
    _Float16*       pkl  = (_Float16*)alloc((size_t)4 * 16384 * 2);

    hipMemsetAsync(deg, 0, (size_t)N_NODES * 4, stream);

    detect_kernel<<<1, 256, 0, stream>>>(ei, flag);
    prep_kernel<<<EDGE_BLKS + CVT_BLKS + PACK_BLKS, 256, 0, stream>>>(
        x, xh, ei, flag, deg, ell, W0, W1, W2, hW1, pkh, pkl);

    int ngb = (N_NODES + 63) / 64; // 782
    // layer 0: xh -> hA
    layer_fused<<<ngb, 256, 0, stream>>>(xh, deg, ell, pkh, pkl, b0, g0, be0, hA, N_NODES);
    // layer 1: hA -> hB
    layer_fused<<<ngb, 256, 0, stream>>>(hA, deg, ell, pkh + (size_t)16384, pkl + (size_t)16384,
                                         b1, g1, be1, hB, N_NODES);
    // layer 2: hB -> hA
    layer_fused<<<ngb, 256, 0, stream>>>(hB, deg, ell, pkh + (size_t)2 * 16384, pkl + (size_t)2 * 16384,
                                         b2, g2, be2, hA, N_NODES);
    // head: ReLU(hA @ hW1 + hb1) @ hW2 + hb2 -> logits
    head_mfma<<<ngb, 256, 0, stream>>>(hA, pkh + (size_t)3 * 16384, pkl + (size_t)3 * 16384,
                                       hb1, hW2, hb2, out, N_NODES);
}